// Round 16
// baseline (292.469 us; speedup 1.0000x reference)
//
#include <hip/hip_runtime.h>

typedef __attribute__((ext_vector_type(4))) float f32x4;
typedef __attribute__((ext_vector_type(2))) float f32x2;
typedef __attribute__((ext_vector_type(8))) short bf16x8;
typedef __attribute__((ext_vector_type(4))) int i32x4;

#define HIST_RANGE 8192   // per-class LDS capacity (8 classes -> n <= 65536)

__device__ __forceinline__ unsigned short bf16_rne(float f) {
    unsigned int u = __float_as_uint(f);
    u += 0x7fffu + ((u >> 16) & 1u);
    return (unsigned short)(u >> 16);
}

__device__ __forceinline__ void split_bf16(float f, unsigned short& hi, unsigned short& lo) {
    unsigned int u = __float_as_uint(f);
    hi = (unsigned short)(u >> 16);                       // truncate
    float r = f - __uint_as_float((unsigned int)hi << 16);
    lo = (unsigned short)(__float_as_uint(r) >> 16);
}

__device__ __forceinline__ unsigned char fp8_e4m3(float f) {
    int p = __builtin_amdgcn_cvt_pk_fp8_f32(f, 0.f, 0, false);   // OCP e4m3 on gfx950
    return (unsigned char)(p & 0xff);
}

// ---------------- edge-index detection + conversion ----------------

__global__ void k_detect(const unsigned int* ei, int* flag) {
    if (blockIdx.x == 0 && threadIdx.x == 0) {
        int is64 = 1;
        for (int i = 0; i < 64; ++i) {
            if (ei[2 * i + 1] != 0u) { is64 = 0; break; }
        }
        *flag = is64;
    }
}

__global__ void k_convert(const void* ei, int twoE, const int* flag, int* __restrict__ out) {
    int p = blockIdx.x * blockDim.x + threadIdx.x;
    int b = p * 2;
    if (b + 1 < twoE) {
        if (*flag) {
            i32x4 v = *(const i32x4*)((const long long*)ei + b);
            int2 o; o.x = v.x; o.y = v.z;
            *(int2*)(out + b) = o;
        } else {
            *(int2*)(out + b) = *(const int2*)((const int*)ei + b);
        }
    } else if (b < twoE) {
        out[b] = (*flag) ? (int)((const long long*)ei)[b] : ((const int*)ei)[b];
    }
}

__global__ void k_hist_atomic(const int* __restrict__ dst, int E, int* __restrict__ cnt) {
    int e = blockIdx.x * blockDim.x + threadIdx.x;
    if (e < E) atomicAdd(&cnt[dst[e]], 1);
}

// ---------------- LDS-privatized, dst-range-partitioned histogram ----------------

__global__ __launch_bounds__(256) void k_hist_part(
    const int* __restrict__ dst, int E, int n, int nrep, int* __restrict__ partial)
{
    __shared__ int h[HIST_RANGE];
    const int cls = blockIdx.x & 7;
    const int rep = blockIdx.x >> 3;
    const int range = (n + 7) >> 3;
    const int lo = cls * range;
    const int hi = min(n, lo + range);
    const int cr = hi - lo;
    if (cr <= 0) return;
    for (int i = threadIdx.x; i < cr; i += 256) h[i] = 0;
    __syncthreads();
    const int chunk = (((E + nrep - 1) / nrep) + 1023) & ~1023;
    const int ebeg = rep * chunk;
    const int eend = min(E, ebeg + chunk);
    if ((E & 3) == 0) {
        for (int e = ebeg + (int)threadIdx.x * 4; e < eend; e += 1024) {
            i32x4 d4 = __builtin_nontemporal_load((const i32x4*)(dst + e));
            if (d4.x >= lo && d4.x < hi) atomicAdd(&h[d4.x - lo], 1);
            if (d4.y >= lo && d4.y < hi) atomicAdd(&h[d4.y - lo], 1);
            if (d4.z >= lo && d4.z < hi) atomicAdd(&h[d4.z - lo], 1);
            if (d4.w >= lo && d4.w < hi) atomicAdd(&h[d4.w - lo], 1);
        }
    } else {
        for (int e = ebeg + (int)threadIdx.x; e < eend; e += 256) {
            int d = __builtin_nontemporal_load(&dst[e]);
            if (d >= lo && d < hi) atomicAdd(&h[d - lo], 1);
        }
    }
    __syncthreads();
    int* po = partial + (size_t)rep * n + lo;
    for (int i = threadIdx.x; i < cr; i += 256) po[i] = h[i];
}

// ---------------- scan: per-rep bases + cnt + exclusive rowptr ----------------

__global__ __launch_bounds__(512) void k_scan1(
    const int* __restrict__ partial, int nrep, int n,
    int* __restrict__ cnt, int* __restrict__ rowptr, int* __restrict__ bsum,
    int* __restrict__ base)
{
    __shared__ int part[512];
    const int t = threadIdx.x;
    const int i = blockIdx.x * 512 + t;
    int own = 0;
    if (i < n) {
        for (int r = 0; r < nrep; ++r) {
            base[(size_t)r * n + i] = own;
            own += partial[(size_t)r * n + i];
        }
        cnt[i] = own;
    }
    part[t] = own;
    __syncthreads();
#pragma unroll
    for (int off = 1; off < 512; off <<= 1) {
        int v = (t >= off) ? part[t - off] : 0;
        __syncthreads();
        part[t] += v;
        __syncthreads();
    }
    if (i < n) rowptr[i] = part[t] - own;
    if (t == 511) bsum[blockIdx.x] = part[511];
}

__global__ __launch_bounds__(256) void k_scan2(const int* __restrict__ bsum, int nb,
                                               int* __restrict__ bofs) {
    __shared__ int part[256];
    const int t = threadIdx.x;
    int own = (t < nb) ? bsum[t] : 0;
    part[t] = own;
    __syncthreads();
#pragma unroll
    for (int off = 1; off < 256; off <<= 1) {
        int v = (t >= off) ? part[t - off] : 0;
        __syncthreads();
        part[t] += v;
        __syncthreads();
    }
    if (t < nb) bofs[t] = part[t] - own;
}

__global__ void k_scan3(const int* __restrict__ cnt, int n, int E,
                        const int* __restrict__ bofs, int* __restrict__ rowptr,
                        int* __restrict__ cursor, float* __restrict__ dinv) {
    int i = blockIdx.x * blockDim.x + threadIdx.x;
    if (i >= n) return;
    int rp = rowptr[i] + bofs[i >> 9];
    rowptr[i] = rp;
    cursor[i] = rp;
    dinv[i] = rsqrtf((float)(cnt[i] + 1));
    if (i == 0) rowptr[n] = E;
}

// ---------------- CSR fill: LDS cursors, NO global atomics ----------------

__global__ __launch_bounds__(256) void k_fill_np(
    const int* __restrict__ src, const int* __restrict__ dst, int E, int n, int nrep,
    const int* __restrict__ rowptr, const int* __restrict__ base, int* __restrict__ csr)
{
    __shared__ int cur[HIST_RANGE];
    const int cls = blockIdx.x & 7;
    const int rep = blockIdx.x >> 3;
    const int range = (n + 7) >> 3;
    const int lo = cls * range;
    const int hi = min(n, lo + range);
    const int cr = hi - lo;
    if (cr <= 0) return;
    const int* bp = base + (size_t)rep * n + lo;
    for (int i = threadIdx.x; i < cr; i += 256) cur[i] = rowptr[lo + i] + bp[i];
    __syncthreads();
    const int chunk = (((E + nrep - 1) / nrep) + 1023) & ~1023;
    const int ebeg = rep * chunk;
    const int eend = min(E, ebeg + chunk);
    if ((E & 3) == 0) {
        for (int e = ebeg + (int)threadIdx.x * 4; e < eend; e += 1024) {
            i32x4 d4 = __builtin_nontemporal_load((const i32x4*)(dst + e));
            bool m0 = d4.x >= lo && d4.x < hi;
            bool m1 = d4.y >= lo && d4.y < hi;
            bool m2 = d4.z >= lo && d4.z < hi;
            bool m3 = d4.w >= lo && d4.w < hi;
            if (m0 | m1 | m2 | m3) {
                i32x4 s4 = __builtin_nontemporal_load((const i32x4*)(src + e));
                if (m0) { int p = atomicAdd(&cur[d4.x - lo], 1); csr[p] = s4.x; }
                if (m1) { int p = atomicAdd(&cur[d4.y - lo], 1); csr[p] = s4.y; }
                if (m2) { int p = atomicAdd(&cur[d4.z - lo], 1); csr[p] = s4.z; }
                if (m3) { int p = atomicAdd(&cur[d4.w - lo], 1); csr[p] = s4.w; }
            }
        }
    } else {
        for (int e = ebeg + (int)threadIdx.x; e < eend; e += 256) {
            int d = __builtin_nontemporal_load(&dst[e]);
            if (d >= lo && d < hi) {
                int s = __builtin_nontemporal_load(&src[e]);
                int p = atomicAdd(&cur[d - lo], 1);
                csr[p] = s;
            }
        }
    }
}

__global__ __launch_bounds__(256) void k_fill_part(
    const int* __restrict__ src, const int* __restrict__ dst, int E, int n,
    int* __restrict__ cursor, int* __restrict__ csr)
{
    const int range = blockIdx.x & 7;
    const int chunk = blockIdx.x >> 3;
    const int nchunks = gridDim.x >> 3;
    const int lo = (int)(((long long)n * range) >> 3);
    const int hi = (int)(((long long)n * (range + 1)) >> 3);
    for (int e = chunk * 256 + (int)threadIdx.x; e < E; e += nchunks * 256) {
        int d = __builtin_nontemporal_load(&dst[e]);
        if (d >= lo && d < hi) {
            int s = __builtin_nontemporal_load(&src[e]);
            int pos = atomicAdd(&cursor[d], 1);
            csr[pos] = s;
        }
    }
}

// ---------------- fp32 -> bf16 (RNE) streaming convert (for x, gx) ----------------

__global__ __launch_bounds__(256) void k_split(const float* __restrict__ in,
                                               unsigned short* __restrict__ O, int n8) {
    int i = blockIdx.x * blockDim.x + threadIdx.x;
    if (i >= n8) return;
    f32x4 v0 = ((const f32x4*)in)[i * 2];
    f32x4 v1 = ((const f32x4*)in)[i * 2 + 1];
    bf16x8 o;
#pragma unroll
    for (int j = 0; j < 8; ++j) {
        float f = (j < 4) ? v0[j] : v1[j - 4];
        o[j] = (short)bf16_rne(f);
    }
    *(bf16x8*)(O + (size_t)i * 8) = o;
}

// ---------------- weight conversion: fp32 [K,F] -> fragment-ordered bf16 hi/lo ----------------

__global__ void k_wconv(const float* __restrict__ W, int K, int F,
                        unsigned short* __restrict__ WH, unsigned short* __restrict__ WL) {
    int idx = blockIdx.x * blockDim.x + threadIdx.x;
    int total = (K / 32) * (F / 16) * 64;
    if (idx >= total) return;
    int lane = idx & 63;
    int t = idx >> 6;
    int CT = F / 16;
    int ks = t / CT, ct = t % CT;
    int col = ct * 16 + (lane & 15);
    int kbase = ks * 32 + (lane >> 4) * 8;
    bf16x8 h, l;
#pragma unroll
    for (int j = 0; j < 8; ++j) {
        unsigned short hi, lo;
        split_bf16(W[(size_t)(kbase + j) * F + col], hi, lo);
        h[j] = (short)hi; l[j] = (short)lo;
    }
    *(bf16x8*)(WH + (size_t)idx * 8) = h;
    *(bf16x8*)(WL + (size_t)idx * 8) = l;
}

// ---------------- LDS-staged MFMA GEMM (single-bf16 A, hi/lo W) ----------------

__device__ __forceinline__ void stage_load(const unsigned short* Ap, int row0, int n, int tid,
                                           bf16x8& s0, bf16x8& s1) {
    int row = tid >> 3;
    int cb = (tid & 7) << 5;
    int gr = min(row0 + row, n - 1);
    const char* gp = (const char*)Ap + ((size_t)gr << 8) + cb;
    s0 = *(const bf16x8*)gp;
    s1 = *(const bf16x8*)(gp + 16);
}

__device__ __forceinline__ void stage_write(unsigned short* td, int tid, bf16x8 s0, bf16x8 s1) {
    int row = tid >> 3;
    int cb = (tid & 7) << 5;
    int s = (row & 7) << 4;
    char* t = (char*)td + row * 256;
    *(bf16x8*)(t + (cb ^ s)) = s0;
    *(bf16x8*)(t + ((cb + 16) ^ s)) = s1;
}

// EPI 0: fp32 out. EPI 1: fp8 e4m3 = dinv*acc. EPI 2: bf16 out (+bias/relu/post).
template<int K, int F, int EPI, bool RELU, bool BIAS, bool SUM2, bool POSTADD>
__global__ __launch_bounds__(256, 3) void k_sgemm(
    const unsigned short* __restrict__ A0, const unsigned short* __restrict__ A1,
    const unsigned short* __restrict__ A2,
    const unsigned short* __restrict__ WH, const unsigned short* __restrict__ WL,
    const float* __restrict__ bias, const float* __restrict__ post,
    const float* __restrict__ dinv, void* __restrict__ o1, int n)
{
    constexpr int CT = F / 16;
    constexpr int CTW = CT / 4;
    constexpr int NCH = K / 128;
    __shared__ unsigned short tile[2][32 * 128];   // 16 KB
    const int tid = threadIdx.x;
    const int lane = tid & 63;
    const int wave = tid >> 6;
    const int row0 = blockIdx.x * 32;
    const int arow = lane & 15;
    const int kgrp = lane >> 4;

    f32x4 acc[2][CTW];
#pragma unroll
    for (int rt = 0; rt < 2; ++rt)
#pragma unroll
        for (int c = 0; c < CTW; ++c) acc[rt][c] = (f32x4)(0.f);

    bf16x8 p0, p1;
    stage_load(A0, row0, n, tid, p0, p1);
    stage_write(tile[0], tid, p0, p1);
    if constexpr (SUM2) {
        stage_load(A1, row0, n, tid, p0, p1);
        stage_write(tile[1], tid, p0, p1);
    }

#pragma unroll
    for (int ch = 0; ch < NCH; ++ch) {
        __syncthreads();
        if (ch + 1 < NCH) {
            const unsigned short* Apn = (ch + 1 == 1) ? A1 : A2;
            stage_load(Apn, row0, n, tid, p0, p1);
        }
        bf16x8 bh[4][CTW], bl[4][CTW];
#pragma unroll
        for (int ks = 0; ks < 4; ++ks)
#pragma unroll
            for (int c = 0; c < CTW; ++c) {
                int ct = wave * CTW + c;
                size_t fo = (((size_t)(ch * 4 + ks) * CT + ct) * 64 + lane) * 8;
                bh[ks][c] = *(const bf16x8*)(WH + fo);
                bl[ks][c] = *(const bf16x8*)(WL + fo);
            }
        int tsrc = SUM2 ? 0 : (ch & 1);
        bf16x8 a[2][4];
#pragma unroll
        for (int rt = 0; rt < 2; ++rt)
#pragma unroll
            for (int ks = 0; ks < 4; ++ks) {
                int row = rt * 16 + arow;
                int cb = (ks * 64 + kgrp * 16) ^ ((row & 7) << 4);
                a[rt][ks] = *(const bf16x8*)((const char*)tile[tsrc] + row * 256 + cb);
            }
        bf16x8 a2f[2][4];
        if constexpr (SUM2) {
#pragma unroll
            for (int rt = 0; rt < 2; ++rt)
#pragma unroll
                for (int ks = 0; ks < 4; ++ks) {
                    int row = rt * 16 + arow;
                    int cb = (ks * 64 + kgrp * 16) ^ ((row & 7) << 4);
                    a2f[rt][ks] = *(const bf16x8*)((const char*)tile[1] + row * 256 + cb);
                }
        }
#pragma unroll
        for (int ks = 0; ks < 4; ++ks)
#pragma unroll
            for (int c = 0; c < CTW; ++c)
#pragma unroll
                for (int rt = 0; rt < 2; ++rt) {
                    acc[rt][c] = __builtin_amdgcn_mfma_f32_16x16x32_bf16(a[rt][ks], bh[ks][c], acc[rt][c], 0, 0, 0);
                    acc[rt][c] = __builtin_amdgcn_mfma_f32_16x16x32_bf16(a[rt][ks], bl[ks][c], acc[rt][c], 0, 0, 0);
                    if constexpr (SUM2) {
                        acc[rt][c] = __builtin_amdgcn_mfma_f32_16x16x32_bf16(a2f[rt][ks], bh[ks][c], acc[rt][c], 0, 0, 0);
                        acc[rt][c] = __builtin_amdgcn_mfma_f32_16x16x32_bf16(a2f[rt][ks], bl[ks][c], acc[rt][c], 0, 0, 0);
                    }
                }
        if (ch + 1 < NCH) stage_write(tile[(ch + 1) & 1], tid, p0, p1);
    }

    // epilogue: D layout col=lane&15, row=(lane>>4)*4+reg  [m89-verified]
    if constexpr (EPI == 1) {
        unsigned char* ob = (unsigned char*)o1;
        float dv[2][4];
#pragma unroll
        for (int rt = 0; rt < 2; ++rt)
#pragma unroll
            for (int r = 0; r < 4; ++r) {
                int row = row0 + rt * 16 + kgrp * 4 + r;
                dv[rt][r] = (row < n) ? dinv[row] : 0.f;
            }
#pragma unroll
        for (int rt = 0; rt < 2; ++rt)
#pragma unroll
            for (int c = 0; c < CTW; ++c) {
                int j = (wave * CTW + c) * 16 + arow;
#pragma unroll
                for (int r = 0; r < 4; ++r) {
                    int row = row0 + rt * 16 + kgrp * 4 + r;
                    if (row < n) ob[(size_t)row * F + j] = fp8_e4m3(acc[rt][c][r] * dv[rt][r]);
                }
            }
    } else if constexpr (EPI == 2) {
        unsigned short* ob = (unsigned short*)o1;
#pragma unroll
        for (int rt = 0; rt < 2; ++rt)
#pragma unroll
            for (int c = 0; c < CTW; ++c) {
                int j = (wave * CTW + c) * 16 + arow;
                float bv = 0.f;
                if constexpr (BIAS) bv = bias[j];
#pragma unroll
                for (int r = 0; r < 4; ++r) {
                    int row = row0 + rt * 16 + kgrp * 4 + r;
                    if (row < n) {
                        float v = acc[rt][c][r];
                        if constexpr (BIAS) v += bv;
                        if constexpr (RELU) v = fmaxf(v, 0.f);
                        if constexpr (POSTADD) v += post[(size_t)row * F + j];
                        ob[(size_t)row * F + j] = bf16_rne(v);
                    }
                }
            }
    } else {
        float* ofp = (float*)o1;
#pragma unroll
        for (int rt = 0; rt < 2; ++rt)
#pragma unroll
            for (int c = 0; c < CTW; ++c) {
                int j = (wave * CTW + c) * 16 + arow;
                float bv = 0.f;
                if constexpr (BIAS) bv = bias[j];
#pragma unroll
                for (int r = 0; r < 4; ++r) {
                    int row = row0 + rt * 16 + kgrp * 4 + r;
                    if (row < n) {
                        float v = acc[rt][c][r];
                        if constexpr (BIAS) v += bv;
                        if constexpr (RELU) v = fmaxf(v, 0.f);
                        if constexpr (POSTADD) v += post[(size_t)row * F + j];
                        ofp[(size_t)row * F + j] = v;
                    }
                }
            }
    }
}

// ---------------- GCN aggregation: fp8 features, 8-deep gather pipeline ----------------

#define ACCW(w) { f32x2 lo_ = __builtin_amdgcn_cvt_pk_f32_fp8((int)(w), false); \
                  f32x2 hi_ = __builtin_amdgcn_cvt_pk_f32_fp8((int)(w), true);  \
                  a0 += lo_.x; a1 += lo_.y; a2 += hi_.x; a3 += hi_.y; }

__global__ __launch_bounds__(256) void k_agg_bf(
    const int* __restrict__ rowptr, const int* __restrict__ csr,
    const float* __restrict__ dinv, const unsigned char* __restrict__ hs,
    const float* __restrict__ bias, unsigned short* __restrict__ outB, int n)
{
    const int node = blockIdx.x * 8 + (threadIdx.x >> 5);
    if (node >= n) return;
    const int c = threadIdx.x & 31;
    const float dd = dinv[node];
    const int beg = rowptr[node];
    const int end = rowptr[node + 1];
    const unsigned int* hw = (const unsigned int*)hs;   // row stride = 32 dwords

    float a0 = 0.f, a1 = 0.f, a2 = 0.f, a3 = 0.f;
    {
        unsigned int w = hw[(size_t)node * 32 + c];
        ACCW(w)
    }

    int j = beg;
    for (; j + 7 < end; j += 8) {
        int s0 = csr[j],     s1 = csr[j + 1], s2 = csr[j + 2], s3 = csr[j + 3];
        int s4 = csr[j + 4], s5 = csr[j + 5], s6 = csr[j + 6], s7 = csr[j + 7];
        unsigned int w0 = hw[(size_t)s0 * 32 + c];
        unsigned int w1 = hw[(size_t)s1 * 32 + c];
        unsigned int w2 = hw[(size_t)s2 * 32 + c];
        unsigned int w3 = hw[(size_t)s3 * 32 + c];
        unsigned int w4 = hw[(size_t)s4 * 32 + c];
        unsigned int w5 = hw[(size_t)s5 * 32 + c];
        unsigned int w6 = hw[(size_t)s6 * 32 + c];
        unsigned int w7 = hw[(size_t)s7 * 32 + c];
        ACCW(w0) ACCW(w1) ACCW(w2) ACCW(w3)
        ACCW(w4) ACCW(w5) ACCW(w6) ACCW(w7)
    }
    for (; j + 3 < end; j += 4) {
        int s0 = csr[j], s1 = csr[j + 1], s2 = csr[j + 2], s3 = csr[j + 3];
        unsigned int w0 = hw[(size_t)s0 * 32 + c];
        unsigned int w1 = hw[(size_t)s1 * 32 + c];
        unsigned int w2 = hw[(size_t)s2 * 32 + c];
        unsigned int w3 = hw[(size_t)s3 * 32 + c];
        ACCW(w0) ACCW(w1) ACCW(w2) ACCW(w3)
    }
    for (; j < end; ++j) {
        unsigned int w = hw[(size_t)csr[j] * 32 + c];
        ACCW(w)
    }

    float4 bv = ((const float4*)bias)[c];
    ushort4 h4;
    h4.x = bf16_rne(fmaxf(fmaf(dd, a0, bv.x), 0.f));
    h4.y = bf16_rne(fmaxf(fmaf(dd, a1, bv.y), 0.f));
    h4.z = bf16_rne(fmaxf(fmaf(dd, a2, bv.z), 0.f));
    h4.w = bf16_rne(fmaxf(fmaf(dd, a3, bv.w), 0.f));
    *(ushort4*)(outB + (size_t)node * 128 + c * 4) = h4;
}

// ---------------- final small GEMM [n,64]@[64,10] ----------------

__global__ __launch_bounds__(256) void k_final(const float* __restrict__ z7, const float* __restrict__ Wo,
                        const float* __restrict__ bo, float* __restrict__ out, int n) {
    __shared__ float Wos[64][10];
    __shared__ float bos[10];
    if (threadIdx.x < 64) {
#pragma unroll
        for (int j = 0; j < 10; ++j) Wos[threadIdx.x][j] = Wo[threadIdx.x * 10 + j];
        if (threadIdx.x < 10) bos[threadIdx.x] = bo[threadIdx.x];
    }
    __syncthreads();
    int idx = blockIdx.x * blockDim.x + threadIdx.x;
    if (idx >= n * 10) return;
    int row = idx / 10, j = idx % 10;
    const float* zr = z7 + (size_t)row * 64;
    float acc = bos[j];
#pragma unroll
    for (int k = 0; k < 64; ++k) acc = fmaf(zr[k], Wos[k][j], acc);
    out[idx] = acc;
}

// ---------------- launch ----------------

extern "C" void kernel_launch(void* const* d_in, const int* in_sizes, int n_in,
                              void* d_out, int out_size, void* d_ws, size_t ws_size,
                              hipStream_t stream) {
    const float* x   = (const float*)d_in[0];
    const float* gx  = (const float*)d_in[1];
    const void*  ei  = d_in[2];
    const float* W1  = (const float*)d_in[3];  const float* b1  = (const float*)d_in[4];
    const float* Wdr = (const float*)d_in[5];  const float* bdr = (const float*)d_in[6];
    const float* Wg1 = (const float*)d_in[7];  const float* bg1 = (const float*)d_in[8];
    const float* Wg2 = (const float*)d_in[9];  const float* bg2 = (const float*)d_in[10];
    const float* W2  = (const float*)d_in[11]; const float* b2  = (const float*)d_in[12];
    const float* W3  = (const float*)d_in[13]; const float* b3  = (const float*)d_in[14];
    const float* Wo  = (const float*)d_in[15]; const float* bo  = (const float*)d_in[16];
    float* out = (float*)d_out;
    const int n = in_sizes[0] / 128;
    const int E = in_sizes[2] / 2;
    const int twoE = 2 * E;
    const int nb = (n + 511) / 512;
    const int NREP = 128;

    char* ws = (char*)d_ws;
    size_t off = 0;
    auto alloc = [&](size_t bytes) -> void* {
        void* p = ws + off;
        off = (off + bytes + 255) & ~(size_t)255;
        return p;
    };
    int*   flag   = (int*)  alloc(256);
    int*   cnt    = (int*)  alloc((size_t)n * 4);
    int*   rowptr = (int*)  alloc(((size_t)n + 1) * 4);
    int*   cursor = (int*)  alloc((size_t)n * 4);
    float* dinv   = (float*)alloc((size_t)n * 4);
    int*   bsum   = (int*)  alloc(1024);
    int*   bofs   = (int*)  alloc(1024);
    int*   es     = (int*)  alloc((size_t)twoE * 4);
    int*   ed     = es + E;
    int*   csr    = (int*)  alloc((size_t)E * 4);
    unsigned short* W1H  = (unsigned short*)alloc(256 * 128 * 2);
    unsigned short* W1L  = (unsigned short*)alloc(256 * 128 * 2);
    unsigned short* WdrH = (unsigned short*)alloc(128 * 128 * 2);
    unsigned short* WdrL = (unsigned short*)alloc(128 * 128 * 2);
    unsigned short* Wg1H = (unsigned short*)alloc(128 * 128 * 2);
    unsigned short* Wg1L = (unsigned short*)alloc(128 * 128 * 2);
    unsigned short* Wg2H = (unsigned short*)alloc(128 * 128 * 2);
    unsigned short* Wg2L = (unsigned short*)alloc(128 * 128 * 2);
    unsigned short* W2H  = (unsigned short*)alloc(384 * 128 * 2);
    unsigned short* W2L  = (unsigned short*)alloc(384 * 128 * 2);
    unsigned short* W3H  = (unsigned short*)alloc(128 * 64 * 2);
    unsigned short* W3L  = (unsigned short*)alloc(128 * 64 * 2);
    const size_t nf = (size_t)n * 128;
    unsigned short* XaB = (unsigned short*)alloc(nf * 2);   // bf16(x)
    unsigned short* XgB = (unsigned short*)alloc(nf * 2);   // bf16(gx)
    // ARENA: prep-phase partial/base (2 * NREP*n*4 B) aliases with post-prep
    // activations (ZB, Z1B, HS, B1) — lifetimes are stream-disjoint:
    // partial/base dead after k_fill_np; ZB/Z1B/HS/B1 written only after it.
    size_t prep_bytes = 2 * ((size_t)NREP * n * 4 + 256);
    size_t act_bytes  = (nf * 2 + 256) * 2 + (nf + 256) + (nf * 4 + 256);
    char* arena = (char*)alloc(prep_bytes > act_bytes ? prep_bytes : act_bytes);
    int* partial = (int*)arena;
    int* base    = (int*)(arena + (((size_t)NREP * n * 4 + 255) & ~(size_t)255));
    char* ap = arena;
    auto carve = [&](size_t bytes) -> void* {
        void* p = ap;
        ap += (bytes + 255) & ~(size_t)255;
        return p;
    };
    unsigned short* ZB  = (unsigned short*)carve(nf * 2);   // bf16(z)
    unsigned short* Z1B = (unsigned short*)carve(nf * 2);   // bf16(z1)
    unsigned char*  HS  = (unsigned char*) carve(nf);       // dinv-scaled fp8 h
    float* B1 = (float*)carve(nf * 4);                      // z0 -> z7 (fp32)
    // stream-ordered aliases (lifetimes disjoint):
    unsigned short* TB  = XaB;  // t: written by GEMM5 (XaB dead after GEMM1)
    unsigned short* Z2B = XgB;  // z2: written by agg2 (XgB dead after GEMM3)
    unsigned char*  HS2 = HS;   // HS dead after agg1
    (void)ws_size; (void)n_in; (void)out_size;

    // edge prep + CSR build
    k_detect<<<1, 64, 0, stream>>>((const unsigned int*)ei, flag);
    k_convert<<<(twoE / 2 + 255) / 256, 256, 0, stream>>>(ei, twoE, flag, es);
    if (n <= 8 * HIST_RANGE) {
        k_hist_part<<<8 * NREP, 256, 0, stream>>>(ed, E, n, NREP, partial);
        k_scan1<<<nb, 512, 0, stream>>>(partial, NREP, n, cnt, rowptr, bsum, base);
        k_scan2<<<1, 256, 0, stream>>>(bsum, nb, bofs);
        k_scan3<<<(n + 255) / 256, 256, 0, stream>>>(cnt, n, E, bofs, rowptr, cursor, dinv);
        k_fill_np<<<8 * NREP, 256, 0, stream>>>(es, ed, E, n, NREP, rowptr, base, csr);
    } else {
        hipMemsetAsync(cnt, 0, (size_t)n * 4, stream);
        k_hist_atomic<<<(E + 255) / 256, 256, 0, stream>>>(ed, E, cnt);
        k_scan1<<<nb, 512, 0, stream>>>(cnt, 1, n, cnt, rowptr, bsum, base);
        k_scan2<<<1, 256, 0, stream>>>(bsum, nb, bofs);
        k_scan3<<<(n + 255) / 256, 256, 0, stream>>>(cnt, n, E, bofs, rowptr, cursor, dinv);
        k_fill_part<<<2048, 256, 0, stream>>>(es, ed, E, n, cursor, csr);
    }

    // weight + activation converts
    k_wconv<<<(256 * 128 + 255) / 256, 256, 0, stream>>>(W1,  256, 128, W1H,  W1L);
    k_wconv<<<(128 * 128 + 255) / 256, 256, 0, stream>>>(Wdr, 128, 128, WdrH, WdrL);
    k_wconv<<<(128 * 128 + 255) / 256, 256, 0, stream>>>(Wg1, 128, 128, Wg1H, Wg1L);
    k_wconv<<<(128 * 128 + 255) / 256, 256, 0, stream>>>(Wg2, 128, 128, Wg2H, Wg2L);
    k_wconv<<<(384 * 128 + 255) / 256, 256, 0, stream>>>(W2,  384, 128, W2H,  W2L);
    k_wconv<<<(128 * 64  + 255) / 256, 256, 0, stream>>>(W3,  128, 64,  W3H,  W3L);
    const int n8 = n * 16;
    k_split<<<(n8 + 255) / 256, 256, 0, stream>>>(x,  XaB, n8);
    k_split<<<(n8 + 255) / 256, 256, 0, stream>>>(gx, XgB, n8);

    const int gm = (n + 31) / 32;
    const int ga = (n + 7) / 8;
    // z = relu([x|gx] @ W1 + b1)  -> ZB
    k_sgemm<256, 128, 2, true,  true,  false, false><<<gm, 256, 0, stream>>>(
        XaB, XgB, nullptr, W1H, W1L, b1, nullptr, nullptr, ZB, n);
    // z0 = z @ Wdr + bdr  -> B1 (fp32)
    k_sgemm<128, 128, 0, false, true,  false, false><<<gm, 256, 0, stream>>>(
        ZB, nullptr, nullptr, WdrH, WdrL, bdr, nullptr, nullptr, B1, n);
    // hs1 = fp8(dinv * ((z + gx) @ Wg1))  [MFMA linearity] -> HS
    k_sgemm<128, 128, 1, false, false, true,  false><<<gm, 256, 0, stream>>>(
        ZB, XgB, nullptr, Wg1H, Wg1L, nullptr, nullptr, dinv, HS, n);
    // z1 = relu(dinv*(hs1[d] + sum hs1[s]) + bg1) -> Z1B
    k_agg_bf<<<ga, 256, 0, stream>>>(rowptr, csr, dinv, HS, bg1, Z1B, n);
    // hs2 = fp8(dinv * (z1 @ Wg2)) -> HS2
    k_sgemm<128, 128, 1, false, false, false, false><<<gm, 256, 0, stream>>>(
        Z1B, nullptr, nullptr, Wg2H, Wg2L, nullptr, nullptr, dinv, HS2, n);
    // z2 = relu(dinv*(hs2[d] + sum hs2[s]) + bg2) -> Z2B
    k_agg_bf<<<ga, 256, 0, stream>>>(rowptr, csr, dinv, HS2, bg2, Z2B, n);
    // t = relu([z|z1|z2] @ W2 + b2) + z0 -> TB
    k_sgemm<384, 128, 2, true,  true,  false, true ><<<gm, 256, 0, stream>>>(
        ZB, Z1B, Z2B, W2H, W2L, b2, B1, nullptr, TB, n);
    // z7 = relu(t @ W3 + b3) -> B1 (fp32)
    k_sgemm<128, 64,  0, true,  true,  false, false><<<gm, 256, 0, stream>>>(
        TB, nullptr, nullptr, W3H, W3L, b3, nullptr, nullptr, B1, n);
    // out = z7 @ Wo + bo
    k_final<<<(n * 10 + 255) / 256, 256, 0, stream>>>(B1, Wo, bo, out, n);
}

// Round 17
// 276.602 us; speedup vs baseline: 1.0574x; 1.0574x over previous
//
#include <hip/hip_runtime.h>

typedef __attribute__((ext_vector_type(4))) float f32x4;
typedef __attribute__((ext_vector_type(2))) float f32x2;
typedef __attribute__((ext_vector_type(8))) short bf16x8;
typedef __attribute__((ext_vector_type(4))) int i32x4;

#define HIST_RANGE 16384   // per-class LDS capacity (4 classes -> n <= 65536)

__device__ __forceinline__ unsigned short bf16_rne(float f) {
    unsigned int u = __float_as_uint(f);
    u += 0x7fffu + ((u >> 16) & 1u);
    return (unsigned short)(u >> 16);
}

__device__ __forceinline__ void split_bf16(float f, unsigned short& hi, unsigned short& lo) {
    unsigned int u = __float_as_uint(f);
    hi = (unsigned short)(u >> 16);                       // truncate
    float r = f - __uint_as_float((unsigned int)hi << 16);
    lo = (unsigned short)(__float_as_uint(r) >> 16);
}

__device__ __forceinline__ unsigned char fp8_e4m3(float f) {
    int p = __builtin_amdgcn_cvt_pk_fp8_f32(f, 0.f, 0, false);   // OCP e4m3 on gfx950
    return (unsigned char)(p & 0xff);
}

// ---------------- edge-index detection + conversion ----------------

__global__ void k_detect(const unsigned int* ei, int* flag) {
    if (blockIdx.x == 0 && threadIdx.x == 0) {
        int is64 = 1;
        for (int i = 0; i < 64; ++i) {
            if (ei[2 * i + 1] != 0u) { is64 = 0; break; }
        }
        *flag = is64;
    }
}

__global__ void k_convert(const void* ei, int twoE, const int* flag, int* __restrict__ out) {
    int p = blockIdx.x * blockDim.x + threadIdx.x;
    int b = p * 2;
    if (b + 1 < twoE) {
        if (*flag) {
            i32x4 v = *(const i32x4*)((const long long*)ei + b);
            int2 o; o.x = v.x; o.y = v.z;
            *(int2*)(out + b) = o;
        } else {
            *(int2*)(out + b) = *(const int2*)((const int*)ei + b);
        }
    } else if (b < twoE) {
        out[b] = (*flag) ? (int)((const long long*)ei)[b] : ((const int*)ei)[b];
    }
}

__global__ void k_hist_atomic(const int* __restrict__ dst, int E, int* __restrict__ cnt) {
    int e = blockIdx.x * blockDim.x + threadIdx.x;
    if (e < E) atomicAdd(&cnt[dst[e]], 1);
}

// ---------------- LDS-privatized, dst-range-partitioned histogram (4 classes) ----------------

__global__ __launch_bounds__(256) void k_hist_part(
    const int* __restrict__ dst, int E, int n, int nrep, unsigned short* __restrict__ partial)
{
    __shared__ int h[HIST_RANGE];
    const int cls = blockIdx.x & 3;
    const int rep = blockIdx.x >> 2;
    const int range = (n + 3) >> 2;
    const int lo = cls * range;
    const int hi = min(n, lo + range);
    const int cr = hi - lo;
    if (cr <= 0) return;
    for (int i = threadIdx.x; i < cr; i += 256) h[i] = 0;
    __syncthreads();
    const int chunk = (((E + nrep - 1) / nrep) + 1023) & ~1023;
    const int ebeg = rep * chunk;
    const int eend = min(E, ebeg + chunk);
    if ((E & 3) == 0) {
        for (int e = ebeg + (int)threadIdx.x * 4; e < eend; e += 1024) {
            i32x4 d4 = __builtin_nontemporal_load((const i32x4*)(dst + e));
            if (d4.x >= lo && d4.x < hi) atomicAdd(&h[d4.x - lo], 1);
            if (d4.y >= lo && d4.y < hi) atomicAdd(&h[d4.y - lo], 1);
            if (d4.z >= lo && d4.z < hi) atomicAdd(&h[d4.z - lo], 1);
            if (d4.w >= lo && d4.w < hi) atomicAdd(&h[d4.w - lo], 1);
        }
    } else {
        for (int e = ebeg + (int)threadIdx.x; e < eend; e += 256) {
            int d = __builtin_nontemporal_load(&dst[e]);
            if (d >= lo && d < hi) atomicAdd(&h[d - lo], 1);
        }
    }
    __syncthreads();
    unsigned short* po = partial + (size_t)rep * n + lo;
    for (int i = threadIdx.x; i < cr; i += 256) po[i] = (unsigned short)h[i];
}

// ---------------- scan: per-rep bases + cnt + exclusive rowptr ----------------

__global__ __launch_bounds__(512) void k_scan1(
    const unsigned short* __restrict__ partial, int nrep, int n,
    int* __restrict__ cnt, int* __restrict__ rowptr, int* __restrict__ bsum,
    unsigned short* __restrict__ base)
{
    __shared__ int part[512];
    const int t = threadIdx.x;
    const int i = blockIdx.x * 512 + t;
    int own = 0;
    if (i < n) {
        for (int r = 0; r < nrep; ++r) {
            base[(size_t)r * n + i] = (unsigned short)own;
            own += partial[(size_t)r * n + i];
        }
        cnt[i] = own;
    }
    part[t] = own;
    __syncthreads();
#pragma unroll
    for (int off = 1; off < 512; off <<= 1) {
        int v = (t >= off) ? part[t - off] : 0;
        __syncthreads();
        part[t] += v;
        __syncthreads();
    }
    if (i < n) rowptr[i] = part[t] - own;
    if (t == 511) bsum[blockIdx.x] = part[511];
}

__global__ __launch_bounds__(256) void k_scan2(const int* __restrict__ bsum, int nb,
                                               int* __restrict__ bofs) {
    __shared__ int part[256];
    const int t = threadIdx.x;
    int own = (t < nb) ? bsum[t] : 0;
    part[t] = own;
    __syncthreads();
#pragma unroll
    for (int off = 1; off < 256; off <<= 1) {
        int v = (t >= off) ? part[t - off] : 0;
        __syncthreads();
        part[t] += v;
        __syncthreads();
    }
    if (t < nb) bofs[t] = part[t] - own;
}

__global__ void k_scan3(const int* __restrict__ cnt, int n, int E,
                        const int* __restrict__ bofs, int* __restrict__ rowptr,
                        int* __restrict__ cursor, float* __restrict__ dinv) {
    int i = blockIdx.x * blockDim.x + threadIdx.x;
    if (i >= n) return;
    int rp = rowptr[i] + bofs[i >> 9];
    rowptr[i] = rp;
    cursor[i] = rp;
    dinv[i] = rsqrtf((float)(cnt[i] + 1));
    if (i == 0) rowptr[n] = E;
}

// ---------------- CSR fill: LDS cursors, NO global atomics (4 classes) ----------------

__global__ __launch_bounds__(256) void k_fill_np(
    const int* __restrict__ src, const int* __restrict__ dst, int E, int n, int nrep,
    const int* __restrict__ rowptr, const unsigned short* __restrict__ base,
    int* __restrict__ csr)
{
    __shared__ int cur[HIST_RANGE];
    const int cls = blockIdx.x & 3;
    const int rep = blockIdx.x >> 2;
    const int range = (n + 3) >> 2;
    const int lo = cls * range;
    const int hi = min(n, lo + range);
    const int cr = hi - lo;
    if (cr <= 0) return;
    const unsigned short* bp = base + (size_t)rep * n + lo;
    for (int i = threadIdx.x; i < cr; i += 256) cur[i] = rowptr[lo + i] + (int)bp[i];
    __syncthreads();
    const int chunk = (((E + nrep - 1) / nrep) + 1023) & ~1023;
    const int ebeg = rep * chunk;
    const int eend = min(E, ebeg + chunk);
    if ((E & 3) == 0) {
        for (int e = ebeg + (int)threadIdx.x * 4; e < eend; e += 1024) {
            i32x4 d4 = __builtin_nontemporal_load((const i32x4*)(dst + e));
            bool m0 = d4.x >= lo && d4.x < hi;
            bool m1 = d4.y >= lo && d4.y < hi;
            bool m2 = d4.z >= lo && d4.z < hi;
            bool m3 = d4.w >= lo && d4.w < hi;
            if (m0 | m1 | m2 | m3) {
                i32x4 s4 = __builtin_nontemporal_load((const i32x4*)(src + e));
                if (m0) { int p = atomicAdd(&cur[d4.x - lo], 1); csr[p] = s4.x; }
                if (m1) { int p = atomicAdd(&cur[d4.y - lo], 1); csr[p] = s4.y; }
                if (m2) { int p = atomicAdd(&cur[d4.z - lo], 1); csr[p] = s4.z; }
                if (m3) { int p = atomicAdd(&cur[d4.w - lo], 1); csr[p] = s4.w; }
            }
        }
    } else {
        for (int e = ebeg + (int)threadIdx.x; e < eend; e += 256) {
            int d = __builtin_nontemporal_load(&dst[e]);
            if (d >= lo && d < hi) {
                int s = __builtin_nontemporal_load(&src[e]);
                int p = atomicAdd(&cur[d - lo], 1);
                csr[p] = s;
            }
        }
    }
}

__global__ __launch_bounds__(256) void k_fill_part(
    const int* __restrict__ src, const int* __restrict__ dst, int E, int n,
    int* __restrict__ cursor, int* __restrict__ csr)
{
    const int range = blockIdx.x & 7;
    const int chunk = blockIdx.x >> 3;
    const int nchunks = gridDim.x >> 3;
    const int lo = (int)(((long long)n * range) >> 3);
    const int hi = (int)(((long long)n * (range + 1)) >> 3);
    for (int e = chunk * 256 + (int)threadIdx.x; e < E; e += nchunks * 256) {
        int d = __builtin_nontemporal_load(&dst[e]);
        if (d >= lo && d < hi) {
            int s = __builtin_nontemporal_load(&src[e]);
            int pos = atomicAdd(&cursor[d], 1);
            csr[pos] = s;
        }
    }
}

// ---------------- fp32 -> bf16 (RNE) streaming convert (for x, gx) ----------------

__global__ __launch_bounds__(256) void k_split(const float* __restrict__ in,
                                               unsigned short* __restrict__ O, int n8) {
    int i = blockIdx.x * blockDim.x + threadIdx.x;
    if (i >= n8) return;
    f32x4 v0 = ((const f32x4*)in)[i * 2];
    f32x4 v1 = ((const f32x4*)in)[i * 2 + 1];
    bf16x8 o;
#pragma unroll
    for (int j = 0; j < 8; ++j) {
        float f = (j < 4) ? v0[j] : v1[j - 4];
        o[j] = (short)bf16_rne(f);
    }
    *(bf16x8*)(O + (size_t)i * 8) = o;
}

// ---------------- weight conversion: fp32 [K,F] -> fragment-ordered bf16 hi/lo ----------------

__global__ void k_wconv(const float* __restrict__ W, int K, int F,
                        unsigned short* __restrict__ WH, unsigned short* __restrict__ WL) {
    int idx = blockIdx.x * blockDim.x + threadIdx.x;
    int total = (K / 32) * (F / 16) * 64;
    if (idx >= total) return;
    int lane = idx & 63;
    int t = idx >> 6;
    int CT = F / 16;
    int ks = t / CT, ct = t % CT;
    int col = ct * 16 + (lane & 15);
    int kbase = ks * 32 + (lane >> 4) * 8;
    bf16x8 h, l;
#pragma unroll
    for (int j = 0; j < 8; ++j) {
        unsigned short hi, lo;
        split_bf16(W[(size_t)(kbase + j) * F + col], hi, lo);
        h[j] = (short)hi; l[j] = (short)lo;
    }
    *(bf16x8*)(WH + (size_t)idx * 8) = h;
    *(bf16x8*)(WL + (size_t)idx * 8) = l;
}

// ---------------- LDS-staged MFMA GEMM (single-bf16 A, hi/lo W) ----------------

__device__ __forceinline__ void stage_load(const unsigned short* Ap, int row0, int n, int tid,
                                           bf16x8& s0, bf16x8& s1) {
    int row = tid >> 3;
    int cb = (tid & 7) << 5;
    int gr = min(row0 + row, n - 1);
    const char* gp = (const char*)Ap + ((size_t)gr << 8) + cb;
    s0 = *(const bf16x8*)gp;
    s1 = *(const bf16x8*)(gp + 16);
}

__device__ __forceinline__ void stage_write(unsigned short* td, int tid, bf16x8 s0, bf16x8 s1) {
    int row = tid >> 3;
    int cb = (tid & 7) << 5;
    int s = (row & 7) << 4;
    char* t = (char*)td + row * 256;
    *(bf16x8*)(t + (cb ^ s)) = s0;
    *(bf16x8*)(t + ((cb + 16) ^ s)) = s1;
}

// EPI 0: fp32 out. EPI 1: fp8 e4m3 = dinv*acc. EPI 2: bf16 out (+bias/relu/post).
template<int K, int F, int EPI, bool RELU, bool BIAS, bool SUM2, bool POSTADD>
__global__ __launch_bounds__(256, 3) void k_sgemm(
    const unsigned short* __restrict__ A0, const unsigned short* __restrict__ A1,
    const unsigned short* __restrict__ A2,
    const unsigned short* __restrict__ WH, const unsigned short* __restrict__ WL,
    const float* __restrict__ bias, const float* __restrict__ post,
    const float* __restrict__ dinv, void* __restrict__ o1, int n)
{
    constexpr int CT = F / 16;
    constexpr int CTW = CT / 4;
    constexpr int NCH = K / 128;
    __shared__ unsigned short tile[2][32 * 128];   // 16 KB
    const int tid = threadIdx.x;
    const int lane = tid & 63;
    const int wave = tid >> 6;
    const int row0 = blockIdx.x * 32;
    const int arow = lane & 15;
    const int kgrp = lane >> 4;

    f32x4 acc[2][CTW];
#pragma unroll
    for (int rt = 0; rt < 2; ++rt)
#pragma unroll
        for (int c = 0; c < CTW; ++c) acc[rt][c] = (f32x4)(0.f);

    bf16x8 p0, p1;
    stage_load(A0, row0, n, tid, p0, p1);
    stage_write(tile[0], tid, p0, p1);
    if constexpr (SUM2) {
        stage_load(A1, row0, n, tid, p0, p1);
        stage_write(tile[1], tid, p0, p1);
    }

#pragma unroll
    for (int ch = 0; ch < NCH; ++ch) {
        __syncthreads();
        if (ch + 1 < NCH) {
            const unsigned short* Apn = (ch + 1 == 1) ? A1 : A2;
            stage_load(Apn, row0, n, tid, p0, p1);
        }
        bf16x8 bh[4][CTW], bl[4][CTW];
#pragma unroll
        for (int ks = 0; ks < 4; ++ks)
#pragma unroll
            for (int c = 0; c < CTW; ++c) {
                int ct = wave * CTW + c;
                size_t fo = (((size_t)(ch * 4 + ks) * CT + ct) * 64 + lane) * 8;
                bh[ks][c] = *(const bf16x8*)(WH + fo);
                bl[ks][c] = *(const bf16x8*)(WL + fo);
            }
        int tsrc = SUM2 ? 0 : (ch & 1);
        bf16x8 a[2][4];
#pragma unroll
        for (int rt = 0; rt < 2; ++rt)
#pragma unroll
            for (int ks = 0; ks < 4; ++ks) {
                int row = rt * 16 + arow;
                int cb = (ks * 64 + kgrp * 16) ^ ((row & 7) << 4);
                a[rt][ks] = *(const bf16x8*)((const char*)tile[tsrc] + row * 256 + cb);
            }
        bf16x8 a2f[2][4];
        if constexpr (SUM2) {
#pragma unroll
            for (int rt = 0; rt < 2; ++rt)
#pragma unroll
                for (int ks = 0; ks < 4; ++ks) {
                    int row = rt * 16 + arow;
                    int cb = (ks * 64 + kgrp * 16) ^ ((row & 7) << 4);
                    a2f[rt][ks] = *(const bf16x8*)((const char*)tile[1] + row * 256 + cb);
                }
        }
#pragma unroll
        for (int ks = 0; ks < 4; ++ks)
#pragma unroll
            for (int c = 0; c < CTW; ++c)
#pragma unroll
                for (int rt = 0; rt < 2; ++rt) {
                    acc[rt][c] = __builtin_amdgcn_mfma_f32_16x16x32_bf16(a[rt][ks], bh[ks][c], acc[rt][c], 0, 0, 0);
                    acc[rt][c] = __builtin_amdgcn_mfma_f32_16x16x32_bf16(a[rt][ks], bl[ks][c], acc[rt][c], 0, 0, 0);
                    if constexpr (SUM2) {
                        acc[rt][c] = __builtin_amdgcn_mfma_f32_16x16x32_bf16(a2f[rt][ks], bh[ks][c], acc[rt][c], 0, 0, 0);
                        acc[rt][c] = __builtin_amdgcn_mfma_f32_16x16x32_bf16(a2f[rt][ks], bl[ks][c], acc[rt][c], 0, 0, 0);
                    }
                }
        if (ch + 1 < NCH) stage_write(tile[(ch + 1) & 1], tid, p0, p1);
    }

    // epilogue: D layout col=lane&15, row=(lane>>4)*4+reg  [m89-verified]
    if constexpr (EPI == 1) {
        unsigned char* ob = (unsigned char*)o1;
        float dv[2][4];
#pragma unroll
        for (int rt = 0; rt < 2; ++rt)
#pragma unroll
            for (int r = 0; r < 4; ++r) {
                int row = row0 + rt * 16 + kgrp * 4 + r;
                dv[rt][r] = (row < n) ? dinv[row] : 0.f;
            }
#pragma unroll
        for (int rt = 0; rt < 2; ++rt)
#pragma unroll
            for (int c = 0; c < CTW; ++c) {
                int j = (wave * CTW + c) * 16 + arow;
#pragma unroll
                for (int r = 0; r < 4; ++r) {
                    int row = row0 + rt * 16 + kgrp * 4 + r;
                    if (row < n) ob[(size_t)row * F + j] = fp8_e4m3(acc[rt][c][r] * dv[rt][r]);
                }
            }
    } else if constexpr (EPI == 2) {
        unsigned short* ob = (unsigned short*)o1;
#pragma unroll
        for (int rt = 0; rt < 2; ++rt)
#pragma unroll
            for (int c = 0; c < CTW; ++c) {
                int j = (wave * CTW + c) * 16 + arow;
                float bv = 0.f;
                if constexpr (BIAS) bv = bias[j];
#pragma unroll
                for (int r = 0; r < 4; ++r) {
                    int row = row0 + rt * 16 + kgrp * 4 + r;
                    if (row < n) {
                        float v = acc[rt][c][r];
                        if constexpr (BIAS) v += bv;
                        if constexpr (RELU) v = fmaxf(v, 0.f);
                        if constexpr (POSTADD) v += post[(size_t)row * F + j];
                        ob[(size_t)row * F + j] = bf16_rne(v);
                    }
                }
            }
    } else {
        float* ofp = (float*)o1;
#pragma unroll
        for (int rt = 0; rt < 2; ++rt)
#pragma unroll
            for (int c = 0; c < CTW; ++c) {
                int j = (wave * CTW + c) * 16 + arow;
                float bv = 0.f;
                if constexpr (BIAS) bv = bias[j];
#pragma unroll
                for (int r = 0; r < 4; ++r) {
                    int row = row0 + rt * 16 + kgrp * 4 + r;
                    if (row < n) {
                        float v = acc[rt][c][r];
                        if constexpr (BIAS) v += bv;
                        if constexpr (RELU) v = fmaxf(v, 0.f);
                        if constexpr (POSTADD) v += post[(size_t)row * F + j];
                        ofp[(size_t)row * F + j] = v;
                    }
                }
            }
    }
}

// ---------------- GCN aggregation: fp8 features, 8-deep gather pipeline ----------------

#define ACCW(w) { f32x2 lo_ = __builtin_amdgcn_cvt_pk_f32_fp8((int)(w), false); \
                  f32x2 hi_ = __builtin_amdgcn_cvt_pk_f32_fp8((int)(w), true);  \
                  a0 += lo_.x; a1 += lo_.y; a2 += hi_.x; a3 += hi_.y; }

__global__ __launch_bounds__(256) void k_agg_bf(
    const int* __restrict__ rowptr, const int* __restrict__ csr,
    const float* __restrict__ dinv, const unsigned char* __restrict__ hs,
    const float* __restrict__ bias, unsigned short* __restrict__ outB, int n)
{
    const int node = blockIdx.x * 8 + (threadIdx.x >> 5);
    if (node >= n) return;
    const int c = threadIdx.x & 31;
    const float dd = dinv[node];
    const int beg = rowptr[node];
    const int end = rowptr[node + 1];
    const unsigned int* hw = (const unsigned int*)hs;   // row stride = 32 dwords

    float a0 = 0.f, a1 = 0.f, a2 = 0.f, a3 = 0.f;
    {
        unsigned int w = hw[(size_t)node * 32 + c];
        ACCW(w)
    }

    int j = beg;
    for (; j + 7 < end; j += 8) {
        int s0 = csr[j],     s1 = csr[j + 1], s2 = csr[j + 2], s3 = csr[j + 3];
        int s4 = csr[j + 4], s5 = csr[j + 5], s6 = csr[j + 6], s7 = csr[j + 7];
        unsigned int w0 = hw[(size_t)s0 * 32 + c];
        unsigned int w1 = hw[(size_t)s1 * 32 + c];
        unsigned int w2 = hw[(size_t)s2 * 32 + c];
        unsigned int w3 = hw[(size_t)s3 * 32 + c];
        unsigned int w4 = hw[(size_t)s4 * 32 + c];
        unsigned int w5 = hw[(size_t)s5 * 32 + c];
        unsigned int w6 = hw[(size_t)s6 * 32 + c];
        unsigned int w7 = hw[(size_t)s7 * 32 + c];
        ACCW(w0) ACCW(w1) ACCW(w2) ACCW(w3)
        ACCW(w4) ACCW(w5) ACCW(w6) ACCW(w7)
    }
    for (; j + 3 < end; j += 4) {
        int s0 = csr[j], s1 = csr[j + 1], s2 = csr[j + 2], s3 = csr[j + 3];
        unsigned int w0 = hw[(size_t)s0 * 32 + c];
        unsigned int w1 = hw[(size_t)s1 * 32 + c];
        unsigned int w2 = hw[(size_t)s2 * 32 + c];
        unsigned int w3 = hw[(size_t)s3 * 32 + c];
        ACCW(w0) ACCW(w1) ACCW(w2) ACCW(w3)
    }
    for (; j < end; ++j) {
        unsigned int w = hw[(size_t)csr[j] * 32 + c];
        ACCW(w)
    }

    float4 bv = ((const float4*)bias)[c];
    ushort4 h4;
    h4.x = bf16_rne(fmaxf(fmaf(dd, a0, bv.x), 0.f));
    h4.y = bf16_rne(fmaxf(fmaf(dd, a1, bv.y), 0.f));
    h4.z = bf16_rne(fmaxf(fmaf(dd, a2, bv.z), 0.f));
    h4.w = bf16_rne(fmaxf(fmaf(dd, a3, bv.w), 0.f));
    *(ushort4*)(outB + (size_t)node * 128 + c * 4) = h4;
}

// ---------------- final small GEMM [n,64]@[64,10] ----------------

__global__ __launch_bounds__(256) void k_final(const float* __restrict__ z7, const float* __restrict__ Wo,
                        const float* __restrict__ bo, float* __restrict__ out, int n) {
    __shared__ float Wos[64][10];
    __shared__ float bos[10];
    if (threadIdx.x < 64) {
#pragma unroll
        for (int j = 0; j < 10; ++j) Wos[threadIdx.x][j] = Wo[threadIdx.x * 10 + j];
        if (threadIdx.x < 10) bos[threadIdx.x] = bo[threadIdx.x];
    }
    __syncthreads();
    int idx = blockIdx.x * blockDim.x + threadIdx.x;
    if (idx >= n * 10) return;
    int row = idx / 10, j = idx % 10;
    const float* zr = z7 + (size_t)row * 64;
    float acc = bos[j];
#pragma unroll
    for (int k = 0; k < 64; ++k) acc = fmaf(zr[k], Wos[k][j], acc);
    out[idx] = acc;
}

// ---------------- launch ----------------

extern "C" void kernel_launch(void* const* d_in, const int* in_sizes, int n_in,
                              void* d_out, int out_size, void* d_ws, size_t ws_size,
                              hipStream_t stream) {
    const float* x   = (const float*)d_in[0];
    const float* gx  = (const float*)d_in[1];
    const void*  ei  = d_in[2];
    const float* W1  = (const float*)d_in[3];  const float* b1  = (const float*)d_in[4];
    const float* Wdr = (const float*)d_in[5];  const float* bdr = (const float*)d_in[6];
    const float* Wg1 = (const float*)d_in[7];  const float* bg1 = (const float*)d_in[8];
    const float* Wg2 = (const float*)d_in[9];  const float* bg2 = (const float*)d_in[10];
    const float* W2  = (const float*)d_in[11]; const float* b2  = (const float*)d_in[12];
    const float* W3  = (const float*)d_in[13]; const float* b3  = (const float*)d_in[14];
    const float* Wo  = (const float*)d_in[15]; const float* bo  = (const float*)d_in[16];
    float* out = (float*)d_out;
    const int n = in_sizes[0] / 128;
    const int E = in_sizes[2] / 2;
    const int twoE = 2 * E;
    const int nb = (n + 511) / 512;
    const int NREP = 128;

    char* ws = (char*)d_ws;
    size_t off = 0;
    auto alloc = [&](size_t bytes) -> void* {
        void* p = ws + off;
        off = (off + bytes + 255) & ~(size_t)255;
        return p;
    };
    int*   flag   = (int*)  alloc(256);
    int*   cnt    = (int*)  alloc((size_t)n * 4);
    int*   rowptr = (int*)  alloc(((size_t)n + 1) * 4);
    int*   cursor = (int*)  alloc((size_t)n * 4);
    float* dinv   = (float*)alloc((size_t)n * 4);
    int*   bsum   = (int*)  alloc(1024);
    int*   bofs   = (int*)  alloc(1024);
    int*   es     = (int*)  alloc((size_t)twoE * 4);
    int*   ed     = es + E;
    int*   csr    = (int*)  alloc((size_t)E * 4);
    unsigned short* W1H  = (unsigned short*)alloc(256 * 128 * 2);
    unsigned short* W1L  = (unsigned short*)alloc(256 * 128 * 2);
    unsigned short* WdrH = (unsigned short*)alloc(128 * 128 * 2);
    unsigned short* WdrL = (unsigned short*)alloc(128 * 128 * 2);
    unsigned short* Wg1H = (unsigned short*)alloc(128 * 128 * 2);
    unsigned short* Wg1L = (unsigned short*)alloc(128 * 128 * 2);
    unsigned short* Wg2H = (unsigned short*)alloc(128 * 128 * 2);
    unsigned short* Wg2L = (unsigned short*)alloc(128 * 128 * 2);
    unsigned short* W2H  = (unsigned short*)alloc(384 * 128 * 2);
    unsigned short* W2L  = (unsigned short*)alloc(384 * 128 * 2);
    unsigned short* W3H  = (unsigned short*)alloc(128 * 64 * 2);
    unsigned short* W3L  = (unsigned short*)alloc(128 * 64 * 2);
    const size_t nf = (size_t)n * 128;
    unsigned short* XaB = (unsigned short*)alloc(nf * 2);   // bf16(x)
    unsigned short* XgB = (unsigned short*)alloc(nf * 2);   // bf16(gx)
    // ARENA: prep-phase partial/base (2 * NREP*n*2 B, ushort) aliases with
    // post-prep activations (ZB, Z1B, HS, B1) — lifetimes stream-disjoint.
    size_t prep_bytes = 2 * ((size_t)NREP * n * 2 + 256);
    size_t act_bytes  = (nf * 2 + 256) * 2 + (nf + 256) + (nf * 4 + 256);
    char* arena = (char*)alloc(prep_bytes > act_bytes ? prep_bytes : act_bytes);
    unsigned short* partial = (unsigned short*)arena;
    unsigned short* base    = (unsigned short*)(arena + (((size_t)NREP * n * 2 + 255) & ~(size_t)255));
    char* ap = arena;
    auto carve = [&](size_t bytes) -> void* {
        void* p = ap;
        ap += (bytes + 255) & ~(size_t)255;
        return p;
    };
    unsigned short* ZB  = (unsigned short*)carve(nf * 2);   // bf16(z)
    unsigned short* Z1B = (unsigned short*)carve(nf * 2);   // bf16(z1)
    unsigned char*  HS  = (unsigned char*) carve(nf);       // dinv-scaled fp8 h
    float* B1 = (float*)carve(nf * 4);                      // z0 -> z7 (fp32)
    // stream-ordered aliases (lifetimes disjoint):
    unsigned short* TB  = XaB;  // t: written by GEMM5 (XaB dead after GEMM1)
    unsigned short* Z2B = XgB;  // z2: written by agg2 (XgB dead after GEMM3)
    unsigned char*  HS2 = HS;   // HS dead after agg1
    (void)ws_size; (void)n_in; (void)out_size;

    // edge prep + CSR build
    k_detect<<<1, 64, 0, stream>>>((const unsigned int*)ei, flag);
    k_convert<<<(twoE / 2 + 255) / 256, 256, 0, stream>>>(ei, twoE, flag, es);
    if (n <= 4 * HIST_RANGE) {
        k_hist_part<<<4 * NREP, 256, 0, stream>>>(ed, E, n, NREP, partial);
        k_scan1<<<nb, 512, 0, stream>>>(partial, NREP, n, cnt, rowptr, bsum, base);
        k_scan2<<<1, 256, 0, stream>>>(bsum, nb, bofs);
        k_scan3<<<(n + 255) / 256, 256, 0, stream>>>(cnt, n, E, bofs, rowptr, cursor, dinv);
        k_fill_np<<<4 * NREP, 256, 0, stream>>>(es, ed, E, n, NREP, rowptr, base, csr);
    } else {
        hipMemsetAsync(cnt, 0, (size_t)n * 4, stream);
        k_hist_atomic<<<(E + 255) / 256, 256, 0, stream>>>(ed, E, cnt);
        // reuse scan1 with nrep=1 over int path is unavailable (ushort partial);
        // large-n fallback: treat cnt directly.
        k_scan1<<<nb, 512, 0, stream>>>((const unsigned short*)nullptr, 0, n, cnt, rowptr, bsum, base);
        k_scan2<<<1, 256, 0, stream>>>(bsum, nb, bofs);
        k_scan3<<<(n + 255) / 256, 256, 0, stream>>>(cnt, n, E, bofs, rowptr, cursor, dinv);
        k_fill_part<<<2048, 256, 0, stream>>>(es, ed, E, n, cursor, csr);
    }

    // weight + activation converts
    k_wconv<<<(256 * 128 + 255) / 256, 256, 0, stream>>>(W1,  256, 128, W1H,  W1L);
    k_wconv<<<(128 * 128 + 255) / 256, 256, 0, stream>>>(Wdr, 128, 128, WdrH, WdrL);
    k_wconv<<<(128 * 128 + 255) / 256, 256, 0, stream>>>(Wg1, 128, 128, Wg1H, Wg1L);
    k_wconv<<<(128 * 128 + 255) / 256, 256, 0, stream>>>(Wg2, 128, 128, Wg2H, Wg2L);
    k_wconv<<<(384 * 128 + 255) / 256, 256, 0, stream>>>(W2,  384, 128, W2H,  W2L);
    k_wconv<<<(128 * 64  + 255) / 256, 256, 0, stream>>>(W3,  128, 64,  W3H,  W3L);
    const int n8 = n * 16;
    k_split<<<(n8 + 255) / 256, 256, 0, stream>>>(x,  XaB, n8);
    k_split<<<(n8 + 255) / 256, 256, 0, stream>>>(gx, XgB, n8);

    const int gm = (n + 31) / 32;
    const int ga = (n + 7) / 8;
    // z = relu([x|gx] @ W1 + b1)  -> ZB
    k_sgemm<256, 128, 2, true,  true,  false, false><<<gm, 256, 0, stream>>>(
        XaB, XgB, nullptr, W1H, W1L, b1, nullptr, nullptr, ZB, n);
    // z0 = z @ Wdr + bdr  -> B1 (fp32)
    k_sgemm<128, 128, 0, false, true,  false, false><<<gm, 256, 0, stream>>>(
        ZB, nullptr, nullptr, WdrH, WdrL, bdr, nullptr, nullptr, B1, n);
    // hs1 = fp8(dinv * ((z + gx) @ Wg1))  [MFMA linearity] -> HS
    k_sgemm<128, 128, 1, false, false, true,  false><<<gm, 256, 0, stream>>>(
        ZB, XgB, nullptr, Wg1H, Wg1L, nullptr, nullptr, dinv, HS, n);
    // z1 = relu(dinv*(hs1[d] + sum hs1[s]) + bg1) -> Z1B
    k_agg_bf<<<ga, 256, 0, stream>>>(rowptr, csr, dinv, HS, bg1, Z1B, n);
    // hs2 = fp8(dinv * (z1 @ Wg2)) -> HS2
    k_sgemm<128, 128, 1, false, false, false, false><<<gm, 256, 0, stream>>>(
        Z1B, nullptr, nullptr, Wg2H, Wg2L, nullptr, nullptr, dinv, HS2, n);
    // z2 = relu(dinv*(hs2[d] + sum hs2[s]) + bg2) -> Z2B
    k_agg_bf<<<ga, 256, 0, stream>>>(rowptr, csr, dinv, HS2, bg2, Z2B, n);
    // t = relu([z|z1|z2] @ W2 + b2) + z0 -> TB
    k_sgemm<384, 128, 2, true,  true,  false, true ><<<gm, 256, 0, stream>>>(
        ZB, Z1B, Z2B, W2H, W2L, b2, B1, nullptr, TB, n);
    // z7 = relu(t @ W3 + b3) -> B1 (fp32)
    k_sgemm<128, 64,  0, true,  true,  false, false><<<gm, 256, 0, stream>>>(
        TB, nullptr, nullptr, W3H, W3L, b3, nullptr, nullptr, B1, n);
    // out = z7 @ Wo + bo
    k_final<<<(n * 10 + 255) / 256, 256, 0, stream>>>(B1, Wo, bo, out, n);
}

// Round 18
// 265.328 us; speedup vs baseline: 1.1023x; 1.0425x over previous
//
#include <hip/hip_runtime.h>

typedef __attribute__((ext_vector_type(4))) float f32x4;
typedef __attribute__((ext_vector_type(2))) float f32x2;
typedef __attribute__((ext_vector_type(8))) short bf16x8;
typedef __attribute__((ext_vector_type(4))) int i32x4;

#define HIST_RANGE 16384   // per-class LDS capacity (4 classes -> n <= 65536)

__device__ __forceinline__ unsigned short bf16_rne(float f) {
    unsigned int u = __float_as_uint(f);
    u += 0x7fffu + ((u >> 16) & 1u);
    return (unsigned short)(u >> 16);
}

__device__ __forceinline__ void split_bf16(float f, unsigned short& hi, unsigned short& lo) {
    unsigned int u = __float_as_uint(f);
    hi = (unsigned short)(u >> 16);                       // truncate
    float r = f - __uint_as_float((unsigned int)hi << 16);
    lo = (unsigned short)(__float_as_uint(r) >> 16);
}

__device__ __forceinline__ unsigned char fp8_e4m3(float f) {
    int p = __builtin_amdgcn_cvt_pk_fp8_f32(f, 0.f, 0, false);   // OCP e4m3 on gfx950
    return (unsigned char)(p & 0xff);
}

// ---------------- edge-index detection + conversion ----------------

__global__ void k_detect(const unsigned int* ei, int* flag) {
    if (blockIdx.x == 0 && threadIdx.x == 0) {
        int is64 = 1;
        for (int i = 0; i < 64; ++i) {
            if (ei[2 * i + 1] != 0u) { is64 = 0; break; }
        }
        *flag = is64;
    }
}

__global__ void k_convert(const void* ei, int twoE, const int* flag, int* __restrict__ out) {
    int p = blockIdx.x * blockDim.x + threadIdx.x;
    int b = p * 2;
    if (b + 1 < twoE) {
        if (*flag) {
            i32x4 v = *(const i32x4*)((const long long*)ei + b);
            int2 o; o.x = v.x; o.y = v.z;
            *(int2*)(out + b) = o;
        } else {
            *(int2*)(out + b) = *(const int2*)((const int*)ei + b);
        }
    } else if (b < twoE) {
        out[b] = (*flag) ? (int)((const long long*)ei)[b] : ((const int*)ei)[b];
    }
}

__global__ void k_hist_atomic(const int* __restrict__ dst, int E, int* __restrict__ cnt) {
    int e = blockIdx.x * blockDim.x + threadIdx.x;
    if (e < E) atomicAdd(&cnt[dst[e]], 1);
}

// ---------------- LDS-privatized, dst-range-partitioned histogram (4 classes, 8-deep) ----------------

__global__ __launch_bounds__(256) void k_hist_part(
    const int* __restrict__ dst, int E, int n, int nrep, unsigned short* __restrict__ partial)
{
    __shared__ int h[HIST_RANGE];
    const int cls = blockIdx.x & 3;
    const int rep = blockIdx.x >> 2;
    const int range = (n + 3) >> 2;
    const int lo = cls * range;
    const int hi = min(n, lo + range);
    const int cr = hi - lo;
    if (cr <= 0) return;
    for (int i = threadIdx.x; i < cr; i += 256) h[i] = 0;
    __syncthreads();
    const int chunk = (((E + nrep - 1) / nrep) + 2047) & ~2047;
    const int ebeg = rep * chunk;
    const int eend = min(E, ebeg + chunk);
    if ((E & 3) == 0) {
        for (int e = ebeg + (int)threadIdx.x * 4; e < eend; e += 2048) {
            i32x4 da = __builtin_nontemporal_load((const i32x4*)(dst + e));
            int e2 = e + 1024;
            bool has2 = e2 < eend;
            i32x4 db;
            if (has2) db = __builtin_nontemporal_load((const i32x4*)(dst + e2));
            if (da.x >= lo && da.x < hi) atomicAdd(&h[da.x - lo], 1);
            if (da.y >= lo && da.y < hi) atomicAdd(&h[da.y - lo], 1);
            if (da.z >= lo && da.z < hi) atomicAdd(&h[da.z - lo], 1);
            if (da.w >= lo && da.w < hi) atomicAdd(&h[da.w - lo], 1);
            if (has2) {
                if (db.x >= lo && db.x < hi) atomicAdd(&h[db.x - lo], 1);
                if (db.y >= lo && db.y < hi) atomicAdd(&h[db.y - lo], 1);
                if (db.z >= lo && db.z < hi) atomicAdd(&h[db.z - lo], 1);
                if (db.w >= lo && db.w < hi) atomicAdd(&h[db.w - lo], 1);
            }
        }
    } else {
        for (int e = ebeg + (int)threadIdx.x; e < eend; e += 256) {
            int d = __builtin_nontemporal_load(&dst[e]);
            if (d >= lo && d < hi) atomicAdd(&h[d - lo], 1);
        }
    }
    __syncthreads();
    unsigned short* po = partial + (size_t)rep * n + lo;
    for (int i = threadIdx.x; i < cr; i += 256) po[i] = (unsigned short)h[i];
}

// ---------------- scan: per-rep bases + cnt + exclusive rowptr ----------------

__global__ __launch_bounds__(512) void k_scan1(
    const unsigned short* __restrict__ partial, int nrep, int n,
    int* __restrict__ cnt, int* __restrict__ rowptr, int* __restrict__ bsum,
    unsigned short* __restrict__ base)
{
    __shared__ int part[512];
    const int t = threadIdx.x;
    const int i = blockIdx.x * 512 + t;
    int own = 0;
    if (i < n) {
        for (int r = 0; r < nrep; ++r) {
            base[(size_t)r * n + i] = (unsigned short)own;
            own += partial[(size_t)r * n + i];
        }
        cnt[i] = own;
    }
    part[t] = own;
    __syncthreads();
#pragma unroll
    for (int off = 1; off < 512; off <<= 1) {
        int v = (t >= off) ? part[t - off] : 0;
        __syncthreads();
        part[t] += v;
        __syncthreads();
    }
    if (i < n) rowptr[i] = part[t] - own;
    if (t == 511) bsum[blockIdx.x] = part[511];
}

__global__ __launch_bounds__(256) void k_scan2(const int* __restrict__ bsum, int nb,
                                               int* __restrict__ bofs) {
    __shared__ int part[256];
    const int t = threadIdx.x;
    int own = (t < nb) ? bsum[t] : 0;
    part[t] = own;
    __syncthreads();
#pragma unroll
    for (int off = 1; off < 256; off <<= 1) {
        int v = (t >= off) ? part[t - off] : 0;
        __syncthreads();
        part[t] += v;
        __syncthreads();
    }
    if (t < nb) bofs[t] = part[t] - own;
}

__global__ void k_scan3(const int* __restrict__ cnt, int n, int E,
                        const int* __restrict__ bofs, int* __restrict__ rowptr,
                        int* __restrict__ cursor, float* __restrict__ dinv) {
    int i = blockIdx.x * blockDim.x + threadIdx.x;
    if (i >= n) return;
    int rp = rowptr[i] + bofs[i >> 9];
    rowptr[i] = rp;
    cursor[i] = rp;
    dinv[i] = rsqrtf((float)(cnt[i] + 1));
    if (i == 0) rowptr[n] = E;
}

// ---------------- CSR fill: LDS cursors, NO global atomics (4 classes, 8-deep) ----------------

__global__ __launch_bounds__(256) void k_fill_np(
    const int* __restrict__ src, const int* __restrict__ dst, int E, int n, int nrep,
    const int* __restrict__ rowptr, const unsigned short* __restrict__ base,
    int* __restrict__ csr)
{
    __shared__ int cur[HIST_RANGE];
    const int cls = blockIdx.x & 3;
    const int rep = blockIdx.x >> 2;
    const int range = (n + 3) >> 2;
    const int lo = cls * range;
    const int hi = min(n, lo + range);
    const int cr = hi - lo;
    if (cr <= 0) return;
    const unsigned short* bp = base + (size_t)rep * n + lo;
    for (int i = threadIdx.x; i < cr; i += 256) cur[i] = rowptr[lo + i] + (int)bp[i];
    __syncthreads();
    const int chunk = (((E + nrep - 1) / nrep) + 2047) & ~2047;
    const int ebeg = rep * chunk;
    const int eend = min(E, ebeg + chunk);
    if ((E & 3) == 0) {
        for (int e = ebeg + (int)threadIdx.x * 4; e < eend; e += 2048) {
            i32x4 da = __builtin_nontemporal_load((const i32x4*)(dst + e));
            int e2 = e + 1024;
            bool has2 = e2 < eend;
            i32x4 db;
            if (has2) db = __builtin_nontemporal_load((const i32x4*)(dst + e2));
            {
                bool m0 = da.x >= lo && da.x < hi;
                bool m1 = da.y >= lo && da.y < hi;
                bool m2 = da.z >= lo && da.z < hi;
                bool m3 = da.w >= lo && da.w < hi;
                if (m0 | m1 | m2 | m3) {
                    i32x4 s4 = __builtin_nontemporal_load((const i32x4*)(src + e));
                    if (m0) { int p = atomicAdd(&cur[da.x - lo], 1); csr[p] = s4.x; }
                    if (m1) { int p = atomicAdd(&cur[da.y - lo], 1); csr[p] = s4.y; }
                    if (m2) { int p = atomicAdd(&cur[da.z - lo], 1); csr[p] = s4.z; }
                    if (m3) { int p = atomicAdd(&cur[da.w - lo], 1); csr[p] = s4.w; }
                }
            }
            if (has2) {
                bool m0 = db.x >= lo && db.x < hi;
                bool m1 = db.y >= lo && db.y < hi;
                bool m2 = db.z >= lo && db.z < hi;
                bool m3 = db.w >= lo && db.w < hi;
                if (m0 | m1 | m2 | m3) {
                    i32x4 s4 = __builtin_nontemporal_load((const i32x4*)(src + e2));
                    if (m0) { int p = atomicAdd(&cur[db.x - lo], 1); csr[p] = s4.x; }
                    if (m1) { int p = atomicAdd(&cur[db.y - lo], 1); csr[p] = s4.y; }
                    if (m2) { int p = atomicAdd(&cur[db.z - lo], 1); csr[p] = s4.z; }
                    if (m3) { int p = atomicAdd(&cur[db.w - lo], 1); csr[p] = s4.w; }
                }
            }
        }
    } else {
        for (int e = ebeg + (int)threadIdx.x; e < eend; e += 256) {
            int d = __builtin_nontemporal_load(&dst[e]);
            if (d >= lo && d < hi) {
                int s = __builtin_nontemporal_load(&src[e]);
                int p = atomicAdd(&cur[d - lo], 1);
                csr[p] = s;
            }
        }
    }
}

__global__ __launch_bounds__(256) void k_fill_part(
    const int* __restrict__ src, const int* __restrict__ dst, int E, int n,
    int* __restrict__ cursor, int* __restrict__ csr)
{
    const int range = blockIdx.x & 7;
    const int chunk = blockIdx.x >> 3;
    const int nchunks = gridDim.x >> 3;
    const int lo = (int)(((long long)n * range) >> 3);
    const int hi = (int)(((long long)n * (range + 1)) >> 3);
    for (int e = chunk * 256 + (int)threadIdx.x; e < E; e += nchunks * 256) {
        int d = __builtin_nontemporal_load(&dst[e]);
        if (d >= lo && d < hi) {
            int s = __builtin_nontemporal_load(&src[e]);
            int pos = atomicAdd(&cursor[d], 1);
            csr[pos] = s;
        }
    }
}

// ---------------- fused fp32 -> bf16 (RNE) convert for x and gx ----------------

__global__ __launch_bounds__(256) void k_split2(const float* __restrict__ x,
                                                const float* __restrict__ gx,
                                                unsigned short* __restrict__ Ox,
                                                unsigned short* __restrict__ Og, int n8) {
    int i = blockIdx.x * blockDim.x + threadIdx.x;
    const float* in; unsigned short* O; int k;
    if (i < n8) { in = x; O = Ox; k = i; }
    else if (i < 2 * n8) { in = gx; O = Og; k = i - n8; }
    else return;
    f32x4 v0 = ((const f32x4*)in)[k * 2];
    f32x4 v1 = ((const f32x4*)in)[k * 2 + 1];
    bf16x8 o;
#pragma unroll
    for (int j = 0; j < 8; ++j) {
        float f = (j < 4) ? v0[j] : v1[j - 4];
        o[j] = (short)bf16_rne(f);
    }
    *(bf16x8*)(O + (size_t)k * 8) = o;
}

// ---------------- fused weight conversion: all 6 weights in one launch ----------------
// fragment slot idx = (ks*(F/16) + ct)*64 + lane; k = ks*32 + (lane>>4)*8 + j; col = ct*16 + (lane&15)

struct WCArgs {
    const float* W[6];
    unsigned short* WH[6];
    unsigned short* WL[6];
    int K[6], F[6];
    int tofs[7];   // thread offsets (each thread = 8 elements)
};

__global__ __launch_bounds__(256) void k_wconv_all(WCArgs a) {
    int idx = blockIdx.x * blockDim.x + threadIdx.x;
    if (idx >= a.tofs[6]) return;
    int s = 0;
    while (idx >= a.tofs[s + 1]) ++s;
    int t0 = idx - a.tofs[s];
    const float* W = a.W[s];
    int K = a.K[s], F = a.F[s];
    int lane = t0 & 63;
    int t = t0 >> 6;
    int CT = F / 16;
    int ks = t / CT, ct = t % CT;
    int col = ct * 16 + (lane & 15);
    int kbase = ks * 32 + (lane >> 4) * 8;
    bf16x8 h, l;
#pragma unroll
    for (int j = 0; j < 8; ++j) {
        unsigned short hi, lo;
        split_bf16(W[(size_t)(kbase + j) * F + col], hi, lo);
        h[j] = (short)hi; l[j] = (short)lo;
    }
    *(bf16x8*)(a.WH[s] + (size_t)t0 * 8) = h;
    *(bf16x8*)(a.WL[s] + (size_t)t0 * 8) = l;
}

// ---------------- LDS-staged MFMA GEMM (single-bf16 A, hi/lo W) ----------------

__device__ __forceinline__ void stage_load(const unsigned short* Ap, int row0, int n, int tid,
                                           bf16x8& s0, bf16x8& s1) {
    int row = tid >> 3;
    int cb = (tid & 7) << 5;
    int gr = min(row0 + row, n - 1);
    const char* gp = (const char*)Ap + ((size_t)gr << 8) + cb;
    s0 = *(const bf16x8*)gp;
    s1 = *(const bf16x8*)(gp + 16);
}

__device__ __forceinline__ void stage_write(unsigned short* td, int tid, bf16x8 s0, bf16x8 s1) {
    int row = tid >> 3;
    int cb = (tid & 7) << 5;
    int s = (row & 7) << 4;
    char* t = (char*)td + row * 256;
    *(bf16x8*)(t + (cb ^ s)) = s0;
    *(bf16x8*)(t + ((cb + 16) ^ s)) = s1;
}

// EPI 0: fp32 out. EPI 1: fp8 e4m3 = dinv*acc. EPI 2: bf16 out (+bias/relu/post).
template<int K, int F, int EPI, bool RELU, bool BIAS, bool SUM2, bool POSTADD>
__global__ __launch_bounds__(256, 3) void k_sgemm(
    const unsigned short* __restrict__ A0, const unsigned short* __restrict__ A1,
    const unsigned short* __restrict__ A2,
    const unsigned short* __restrict__ WH, const unsigned short* __restrict__ WL,
    const float* __restrict__ bias, const float* __restrict__ post,
    const float* __restrict__ dinv, void* __restrict__ o1, int n)
{
    constexpr int CT = F / 16;
    constexpr int CTW = CT / 4;
    constexpr int NCH = K / 128;
    __shared__ unsigned short tile[2][32 * 128];   // 16 KB
    const int tid = threadIdx.x;
    const int lane = tid & 63;
    const int wave = tid >> 6;
    const int row0 = blockIdx.x * 32;
    const int arow = lane & 15;
    const int kgrp = lane >> 4;

    f32x4 acc[2][CTW];
#pragma unroll
    for (int rt = 0; rt < 2; ++rt)
#pragma unroll
        for (int c = 0; c < CTW; ++c) acc[rt][c] = (f32x4)(0.f);

    bf16x8 p0, p1;
    stage_load(A0, row0, n, tid, p0, p1);
    stage_write(tile[0], tid, p0, p1);
    if constexpr (SUM2) {
        stage_load(A1, row0, n, tid, p0, p1);
        stage_write(tile[1], tid, p0, p1);
    }

#pragma unroll
    for (int ch = 0; ch < NCH; ++ch) {
        __syncthreads();
        if (ch + 1 < NCH) {
            const unsigned short* Apn = (ch + 1 == 1) ? A1 : A2;
            stage_load(Apn, row0, n, tid, p0, p1);
        }
        bf16x8 bh[4][CTW], bl[4][CTW];
#pragma unroll
        for (int ks = 0; ks < 4; ++ks)
#pragma unroll
            for (int c = 0; c < CTW; ++c) {
                int ct = wave * CTW + c;
                size_t fo = (((size_t)(ch * 4 + ks) * CT + ct) * 64 + lane) * 8;
                bh[ks][c] = *(const bf16x8*)(WH + fo);
                bl[ks][c] = *(const bf16x8*)(WL + fo);
            }
        int tsrc = SUM2 ? 0 : (ch & 1);
        bf16x8 a[2][4];
#pragma unroll
        for (int rt = 0; rt < 2; ++rt)
#pragma unroll
            for (int ks = 0; ks < 4; ++ks) {
                int row = rt * 16 + arow;
                int cb = (ks * 64 + kgrp * 16) ^ ((row & 7) << 4);
                a[rt][ks] = *(const bf16x8*)((const char*)tile[tsrc] + row * 256 + cb);
            }
        bf16x8 a2f[2][4];
        if constexpr (SUM2) {
#pragma unroll
            for (int rt = 0; rt < 2; ++rt)
#pragma unroll
                for (int ks = 0; ks < 4; ++ks) {
                    int row = rt * 16 + arow;
                    int cb = (ks * 64 + kgrp * 16) ^ ((row & 7) << 4);
                    a2f[rt][ks] = *(const bf16x8*)((const char*)tile[1] + row * 256 + cb);
                }
        }
#pragma unroll
        for (int ks = 0; ks < 4; ++ks)
#pragma unroll
            for (int c = 0; c < CTW; ++c)
#pragma unroll
                for (int rt = 0; rt < 2; ++rt) {
                    acc[rt][c] = __builtin_amdgcn_mfma_f32_16x16x32_bf16(a[rt][ks], bh[ks][c], acc[rt][c], 0, 0, 0);
                    acc[rt][c] = __builtin_amdgcn_mfma_f32_16x16x32_bf16(a[rt][ks], bl[ks][c], acc[rt][c], 0, 0, 0);
                    if constexpr (SUM2) {
                        acc[rt][c] = __builtin_amdgcn_mfma_f32_16x16x32_bf16(a2f[rt][ks], bh[ks][c], acc[rt][c], 0, 0, 0);
                        acc[rt][c] = __builtin_amdgcn_mfma_f32_16x16x32_bf16(a2f[rt][ks], bl[ks][c], acc[rt][c], 0, 0, 0);
                    }
                }
        if (ch + 1 < NCH) stage_write(tile[(ch + 1) & 1], tid, p0, p1);
    }

    // epilogue: D layout col=lane&15, row=(lane>>4)*4+reg  [m89-verified]
    if constexpr (EPI == 1) {
        unsigned char* ob = (unsigned char*)o1;
        float dv[2][4];
#pragma unroll
        for (int rt = 0; rt < 2; ++rt)
#pragma unroll
            for (int r = 0; r < 4; ++r) {
                int row = row0 + rt * 16 + kgrp * 4 + r;
                dv[rt][r] = (row < n) ? dinv[row] : 0.f;
            }
#pragma unroll
        for (int rt = 0; rt < 2; ++rt)
#pragma unroll
            for (int c = 0; c < CTW; ++c) {
                int j = (wave * CTW + c) * 16 + arow;
#pragma unroll
                for (int r = 0; r < 4; ++r) {
                    int row = row0 + rt * 16 + kgrp * 4 + r;
                    if (row < n) ob[(size_t)row * F + j] = fp8_e4m3(acc[rt][c][r] * dv[rt][r]);
                }
            }
    } else if constexpr (EPI == 2) {
        unsigned short* ob = (unsigned short*)o1;
#pragma unroll
        for (int rt = 0; rt < 2; ++rt)
#pragma unroll
            for (int c = 0; c < CTW; ++c) {
                int j = (wave * CTW + c) * 16 + arow;
                float bv = 0.f;
                if constexpr (BIAS) bv = bias[j];
#pragma unroll
                for (int r = 0; r < 4; ++r) {
                    int row = row0 + rt * 16 + kgrp * 4 + r;
                    if (row < n) {
                        float v = acc[rt][c][r];
                        if constexpr (BIAS) v += bv;
                        if constexpr (RELU) v = fmaxf(v, 0.f);
                        if constexpr (POSTADD) v += post[(size_t)row * F + j];
                        ob[(size_t)row * F + j] = bf16_rne(v);
                    }
                }
            }
    } else {
        float* ofp = (float*)o1;
#pragma unroll
        for (int rt = 0; rt < 2; ++rt)
#pragma unroll
            for (int c = 0; c < CTW; ++c) {
                int j = (wave * CTW + c) * 16 + arow;
                float bv = 0.f;
                if constexpr (BIAS) bv = bias[j];
#pragma unroll
                for (int r = 0; r < 4; ++r) {
                    int row = row0 + rt * 16 + kgrp * 4 + r;
                    if (row < n) {
                        float v = acc[rt][c][r];
                        if constexpr (BIAS) v += bv;
                        if constexpr (RELU) v = fmaxf(v, 0.f);
                        if constexpr (POSTADD) v += post[(size_t)row * F + j];
                        ofp[(size_t)row * F + j] = v;
                    }
                }
            }
    }
}

// ---------------- GCN aggregation: fp8 features, 8-deep gather pipeline ----------------

#define ACCW(w) { f32x2 lo_ = __builtin_amdgcn_cvt_pk_f32_fp8((int)(w), false); \
                  f32x2 hi_ = __builtin_amdgcn_cvt_pk_f32_fp8((int)(w), true);  \
                  a0 += lo_.x; a1 += lo_.y; a2 += hi_.x; a3 += hi_.y; }

__global__ __launch_bounds__(256) void k_agg_bf(
    const int* __restrict__ rowptr, const int* __restrict__ csr,
    const float* __restrict__ dinv, const unsigned char* __restrict__ hs,
    const float* __restrict__ bias, unsigned short* __restrict__ outB, int n)
{
    const int node = blockIdx.x * 8 + (threadIdx.x >> 5);
    if (node >= n) return;
    const int c = threadIdx.x & 31;
    const float dd = dinv[node];
    const int beg = rowptr[node];
    const int end = rowptr[node + 1];
    const unsigned int* hw = (const unsigned int*)hs;   // row stride = 32 dwords

    float a0 = 0.f, a1 = 0.f, a2 = 0.f, a3 = 0.f;
    {
        unsigned int w = hw[(size_t)node * 32 + c];
        ACCW(w)
    }

    int j = beg;
    for (; j + 7 < end; j += 8) {
        int s0 = csr[j],     s1 = csr[j + 1], s2 = csr[j + 2], s3 = csr[j + 3];
        int s4 = csr[j + 4], s5 = csr[j + 5], s6 = csr[j + 6], s7 = csr[j + 7];
        unsigned int w0 = hw[(size_t)s0 * 32 + c];
        unsigned int w1 = hw[(size_t)s1 * 32 + c];
        unsigned int w2 = hw[(size_t)s2 * 32 + c];
        unsigned int w3 = hw[(size_t)s3 * 32 + c];
        unsigned int w4 = hw[(size_t)s4 * 32 + c];
        unsigned int w5 = hw[(size_t)s5 * 32 + c];
        unsigned int w6 = hw[(size_t)s6 * 32 + c];
        unsigned int w7 = hw[(size_t)s7 * 32 + c];
        ACCW(w0) ACCW(w1) ACCW(w2) ACCW(w3)
        ACCW(w4) ACCW(w5) ACCW(w6) ACCW(w7)
    }
    for (; j + 3 < end; j += 4) {
        int s0 = csr[j], s1 = csr[j + 1], s2 = csr[j + 2], s3 = csr[j + 3];
        unsigned int w0 = hw[(size_t)s0 * 32 + c];
        unsigned int w1 = hw[(size_t)s1 * 32 + c];
        unsigned int w2 = hw[(size_t)s2 * 32 + c];
        unsigned int w3 = hw[(size_t)s3 * 32 + c];
        ACCW(w0) ACCW(w1) ACCW(w2) ACCW(w3)
    }
    for (; j < end; ++j) {
        unsigned int w = hw[(size_t)csr[j] * 32 + c];
        ACCW(w)
    }

    float4 bv = ((const float4*)bias)[c];
    ushort4 h4;
    h4.x = bf16_rne(fmaxf(fmaf(dd, a0, bv.x), 0.f));
    h4.y = bf16_rne(fmaxf(fmaf(dd, a1, bv.y), 0.f));
    h4.z = bf16_rne(fmaxf(fmaf(dd, a2, bv.z), 0.f));
    h4.w = bf16_rne(fmaxf(fmaf(dd, a3, bv.w), 0.f));
    *(ushort4*)(outB + (size_t)node * 128 + c * 4) = h4;
}

// ---------------- final small GEMM [n,64]@[64,10] ----------------

__global__ __launch_bounds__(256) void k_final(const float* __restrict__ z7, const float* __restrict__ Wo,
                        const float* __restrict__ bo, float* __restrict__ out, int n) {
    __shared__ float Wos[64][10];
    __shared__ float bos[10];
    if (threadIdx.x < 64) {
#pragma unroll
        for (int j = 0; j < 10; ++j) Wos[threadIdx.x][j] = Wo[threadIdx.x * 10 + j];
        if (threadIdx.x < 10) bos[threadIdx.x] = bo[threadIdx.x];
    }
    __syncthreads();
    int idx = blockIdx.x * blockDim.x + threadIdx.x;
    if (idx >= n * 10) return;
    int row = idx / 10, j = idx % 10;
    const float* zr = z7 + (size_t)row * 64;
    float acc = bos[j];
#pragma unroll
    for (int k = 0; k < 64; ++k) acc = fmaf(zr[k], Wos[k][j], acc);
    out[idx] = acc;
}

// ---------------- launch ----------------

extern "C" void kernel_launch(void* const* d_in, const int* in_sizes, int n_in,
                              void* d_out, int out_size, void* d_ws, size_t ws_size,
                              hipStream_t stream) {
    const float* x   = (const float*)d_in[0];
    const float* gx  = (const float*)d_in[1];
    const void*  ei  = d_in[2];
    const float* W1  = (const float*)d_in[3];  const float* b1  = (const float*)d_in[4];
    const float* Wdr = (const float*)d_in[5];  const float* bdr = (const float*)d_in[6];
    const float* Wg1 = (const float*)d_in[7];  const float* bg1 = (const float*)d_in[8];
    const float* Wg2 = (const float*)d_in[9];  const float* bg2 = (const float*)d_in[10];
    const float* W2  = (const float*)d_in[11]; const float* b2  = (const float*)d_in[12];
    const float* W3  = (const float*)d_in[13]; const float* b3  = (const float*)d_in[14];
    const float* Wo  = (const float*)d_in[15]; const float* bo  = (const float*)d_in[16];
    float* out = (float*)d_out;
    const int n = in_sizes[0] / 128;
    const int E = in_sizes[2] / 2;
    const int twoE = 2 * E;
    const int nb = (n + 511) / 512;
    const int NREP = 128;

    char* ws = (char*)d_ws;
    size_t off = 0;
    auto alloc = [&](size_t bytes) -> void* {
        void* p = ws + off;
        off = (off + bytes + 255) & ~(size_t)255;
        return p;
    };
    int*   flag   = (int*)  alloc(256);
    int*   cnt    = (int*)  alloc((size_t)n * 4);
    int*   rowptr = (int*)  alloc(((size_t)n + 1) * 4);
    int*   cursor = (int*)  alloc((size_t)n * 4);
    float* dinv   = (float*)alloc((size_t)n * 4);
    int*   bsum   = (int*)  alloc(1024);
    int*   bofs   = (int*)  alloc(1024);
    int*   es     = (int*)  alloc((size_t)twoE * 4);
    int*   ed     = es + E;
    int*   csr    = (int*)  alloc((size_t)E * 4);
    unsigned short* W1H  = (unsigned short*)alloc(256 * 128 * 2);
    unsigned short* W1L  = (unsigned short*)alloc(256 * 128 * 2);
    unsigned short* WdrH = (unsigned short*)alloc(128 * 128 * 2);
    unsigned short* WdrL = (unsigned short*)alloc(128 * 128 * 2);
    unsigned short* Wg1H = (unsigned short*)alloc(128 * 128 * 2);
    unsigned short* Wg1L = (unsigned short*)alloc(128 * 128 * 2);
    unsigned short* Wg2H = (unsigned short*)alloc(128 * 128 * 2);
    unsigned short* Wg2L = (unsigned short*)alloc(128 * 128 * 2);
    unsigned short* W2H  = (unsigned short*)alloc(384 * 128 * 2);
    unsigned short* W2L  = (unsigned short*)alloc(384 * 128 * 2);
    unsigned short* W3H  = (unsigned short*)alloc(128 * 64 * 2);
    unsigned short* W3L  = (unsigned short*)alloc(128 * 64 * 2);
    const size_t nf = (size_t)n * 128;
    unsigned short* XaB = (unsigned short*)alloc(nf * 2);   // bf16(x)
    unsigned short* XgB = (unsigned short*)alloc(nf * 2);   // bf16(gx)
    // ARENA: prep-phase partial/base (ushort) aliases post-prep activations.
    size_t prep_bytes = 2 * ((size_t)NREP * n * 2 + 256);
    size_t act_bytes  = (nf * 2 + 256) * 2 + (nf + 256) + (nf * 4 + 256);
    char* arena = (char*)alloc(prep_bytes > act_bytes ? prep_bytes : act_bytes);
    unsigned short* partial = (unsigned short*)arena;
    unsigned short* base    = (unsigned short*)(arena + (((size_t)NREP * n * 2 + 255) & ~(size_t)255));
    char* ap = arena;
    auto carve = [&](size_t bytes) -> void* {
        void* p = ap;
        ap += (bytes + 255) & ~(size_t)255;
        return p;
    };
    unsigned short* ZB  = (unsigned short*)carve(nf * 2);   // bf16(z)
    unsigned short* Z1B = (unsigned short*)carve(nf * 2);   // bf16(z1)
    unsigned char*  HS  = (unsigned char*) carve(nf);       // dinv-scaled fp8 h
    float* B1 = (float*)carve(nf * 4);                      // z0 -> z7 (fp32)
    unsigned short* TB  = XaB;  // t: written by GEMM5 (XaB dead after GEMM1)
    unsigned short* Z2B = XgB;  // z2: written by agg2 (XgB dead after GEMM3)
    unsigned char*  HS2 = HS;   // HS dead after agg1
    (void)ws_size; (void)n_in; (void)out_size;

    // edge prep + CSR build
    k_detect<<<1, 64, 0, stream>>>((const unsigned int*)ei, flag);
    k_convert<<<(twoE / 2 + 255) / 256, 256, 0, stream>>>(ei, twoE, flag, es);
    if (n <= 4 * HIST_RANGE) {
        k_hist_part<<<4 * NREP, 256, 0, stream>>>(ed, E, n, NREP, partial);
        k_scan1<<<nb, 512, 0, stream>>>(partial, NREP, n, cnt, rowptr, bsum, base);
        k_scan2<<<1, 256, 0, stream>>>(bsum, nb, bofs);
        k_scan3<<<(n + 255) / 256, 256, 0, stream>>>(cnt, n, E, bofs, rowptr, cursor, dinv);
        k_fill_np<<<4 * NREP, 256, 0, stream>>>(es, ed, E, n, NREP, rowptr, base, csr);
    } else {
        hipMemsetAsync(cnt, 0, (size_t)n * 4, stream);
        k_hist_atomic<<<(E + 255) / 256, 256, 0, stream>>>(ed, E, cnt);
        k_scan1<<<nb, 512, 0, stream>>>((const unsigned short*)nullptr, 0, n, cnt, rowptr, bsum, base);
        k_scan2<<<1, 256, 0, stream>>>(bsum, nb, bofs);
        k_scan3<<<(n + 255) / 256, 256, 0, stream>>>(cnt, n, E, bofs, rowptr, cursor, dinv);
        k_fill_part<<<2048, 256, 0, stream>>>(es, ed, E, n, cursor, csr);
    }

    // fused weight + activation converts
    {
        WCArgs a;
        const float* Ws[6] = { W1, Wdr, Wg1, Wg2, W2, W3 };
        unsigned short* WHs[6] = { W1H, WdrH, Wg1H, Wg2H, W2H, W3H };
        unsigned short* WLs[6] = { W1L, WdrL, Wg1L, Wg2L, W2L, W3L };
        int Ks[6] = { 256, 128, 128, 128, 384, 128 };
        int Fs[6] = { 128, 128, 128, 128, 128, 64 };
        int acc = 0;
        for (int s = 0; s < 6; ++s) {
            a.W[s] = Ws[s]; a.WH[s] = WHs[s]; a.WL[s] = WLs[s];
            a.K[s] = Ks[s]; a.F[s] = Fs[s];
            a.tofs[s] = acc;
            acc += Ks[s] * Fs[s] / 8;
        }
        a.tofs[6] = acc;
        k_wconv_all<<<(acc + 255) / 256, 256, 0, stream>>>(a);
    }
    const int n8 = n * 16;
    k_split2<<<(2 * n8 + 255) / 256, 256, 0, stream>>>(x, gx, XaB, XgB, n8);

    const int gm = (n + 31) / 32;
    const int ga = (n + 7) / 8;
    // z = relu([x|gx] @ W1 + b1)  -> ZB
    k_sgemm<256, 128, 2, true,  true,  false, false><<<gm, 256, 0, stream>>>(
        XaB, XgB, nullptr, W1H, W1L, b1, nullptr, nullptr, ZB, n);
    // z0 = z @ Wdr + bdr  -> B1 (fp32)
    k_sgemm<128, 128, 0, false, true,  false, false><<<gm, 256, 0, stream>>>(
        ZB, nullptr, nullptr, WdrH, WdrL, bdr, nullptr, nullptr, B1, n);
    // hs1 = fp8(dinv * ((z + gx) @ Wg1))  [MFMA linearity] -> HS
    k_sgemm<128, 128, 1, false, false, true,  false><<<gm, 256, 0, stream>>>(
        ZB, XgB, nullptr, Wg1H, Wg1L, nullptr, nullptr, dinv, HS, n);
    // z1 = relu(dinv*(hs1[d] + sum hs1[s]) + bg1) -> Z1B
    k_agg_bf<<<ga, 256, 0, stream>>>(rowptr, csr, dinv, HS, bg1, Z1B, n);
    // hs2 = fp8(dinv * (z1 @ Wg2)) -> HS2
    k_sgemm<128, 128, 1, false, false, false, false><<<gm, 256, 0, stream>>>(
        Z1B, nullptr, nullptr, Wg2H, Wg2L, nullptr, nullptr, dinv, HS2, n);
    // z2 = relu(dinv*(hs2[d] + sum hs2[s]) + bg2) -> Z2B
    k_agg_bf<<<ga, 256, 0, stream>>>(rowptr, csr, dinv, HS2, bg2, Z2B, n);
    // t = relu([z|z1|z2] @ W2 + b2) + z0 -> TB
    k_sgemm<384, 128, 2, true,  true,  false, true ><<<gm, 256, 0, stream>>>(
        ZB, Z1B, Z2B, W2H, W2L, b2, B1, nullptr, TB, n);
    // z7 = relu(t @ W3 + b3) -> B1 (fp32)
    k_sgemm<128, 64,  0, true,  true,  false, false><<<gm, 256, 0, stream>>>(
        TB, nullptr, nullptr, W3H, W3L, b3, nullptr, nullptr, B1, n);
    // out = z7 @ Wo + bo
    k_final<<<(n * 10 + 255) / 256, 256, 0, stream>>>(B1, Wo, bo, out, n);
}

// Round 19
// 258.275 us; speedup vs baseline: 1.1324x; 1.0273x over previous
//
#include <hip/hip_runtime.h>

typedef __attribute__((ext_vector_type(4))) float f32x4;
typedef __attribute__((ext_vector_type(2))) float f32x2;
typedef __attribute__((ext_vector_type(8))) short bf16x8;
typedef __attribute__((ext_vector_type(4))) int i32x4;

#define HIST_RANGE 16384   // per-class LDS capacity (4 classes -> n <= 65536)

__device__ __forceinline__ unsigned short bf16_rne(float f) {
    unsigned int u = __float_as_uint(f);
    u += 0x7fffu + ((u >> 16) & 1u);
    return (unsigned short)(u >> 16);
}

__device__ __forceinline__ void split_bf16(float f, unsigned short& hi, unsigned short& lo) {
    unsigned int u = __float_as_uint(f);
    hi = (unsigned short)(u >> 16);                       // truncate
    float r = f - __uint_as_float((unsigned int)hi << 16);
    lo = (unsigned short)(__float_as_uint(r) >> 16);
}

__device__ __forceinline__ unsigned char fp8_e4m3(float f) {
    int p = __builtin_amdgcn_cvt_pk_fp8_f32(f, 0.f, 0, false);   // OCP e4m3 on gfx950
    return (unsigned char)(p & 0xff);
}

// ---------------- edge-index detection + conversion ----------------

__global__ void k_detect(const unsigned int* ei, int* flag) {
    if (blockIdx.x == 0 && threadIdx.x == 0) {
        int is64 = 1;
        for (int i = 0; i < 64; ++i) {
            if (ei[2 * i + 1] != 0u) { is64 = 0; break; }
        }
        *flag = is64;
    }
}

__global__ void k_convert(const void* ei, int twoE, const int* flag, int* __restrict__ out) {
    int p = blockIdx.x * blockDim.x + threadIdx.x;
    int b = p * 2;
    if (b + 1 < twoE) {
        if (*flag) {
            i32x4 v = *(const i32x4*)((const long long*)ei + b);
            int2 o; o.x = v.x; o.y = v.z;
            *(int2*)(out + b) = o;
        } else {
            *(int2*)(out + b) = *(const int2*)((const int*)ei + b);
        }
    } else if (b < twoE) {
        out[b] = (*flag) ? (int)((const long long*)ei)[b] : ((const int*)ei)[b];
    }
}

__global__ void k_hist_atomic(const int* __restrict__ dst, int E, int* __restrict__ cnt) {
    int e = blockIdx.x * blockDim.x + threadIdx.x;
    if (e < E) atomicAdd(&cnt[dst[e]], 1);
}

// ---------------- LDS-privatized, dst-range-partitioned histogram (4 classes, 8-deep) ----------------

__global__ __launch_bounds__(256) void k_hist_part(
    const int* __restrict__ dst, int E, int n, int nrep, unsigned short* __restrict__ partial)
{
    __shared__ int h[HIST_RANGE];
    const int cls = blockIdx.x & 3;
    const int rep = blockIdx.x >> 2;
    const int range = (n + 3) >> 2;
    const int lo = cls * range;
    const int hi = min(n, lo + range);
    const int cr = hi - lo;
    if (cr <= 0) return;
    for (int i = threadIdx.x; i < cr; i += 256) h[i] = 0;
    __syncthreads();
    const int chunk = (((E + nrep - 1) / nrep) + 2047) & ~2047;
    const int ebeg = rep * chunk;
    const int eend = min(E, ebeg + chunk);
    if ((E & 3) == 0) {
        for (int e = ebeg + (int)threadIdx.x * 4; e < eend; e += 2048) {
            i32x4 da = __builtin_nontemporal_load((const i32x4*)(dst + e));
            int e2 = e + 1024;
            bool has2 = e2 < eend;
            i32x4 db;
            if (has2) db = __builtin_nontemporal_load((const i32x4*)(dst + e2));
            if (da.x >= lo && da.x < hi) atomicAdd(&h[da.x - lo], 1);
            if (da.y >= lo && da.y < hi) atomicAdd(&h[da.y - lo], 1);
            if (da.z >= lo && da.z < hi) atomicAdd(&h[da.z - lo], 1);
            if (da.w >= lo && da.w < hi) atomicAdd(&h[da.w - lo], 1);
            if (has2) {
                if (db.x >= lo && db.x < hi) atomicAdd(&h[db.x - lo], 1);
                if (db.y >= lo && db.y < hi) atomicAdd(&h[db.y - lo], 1);
                if (db.z >= lo && db.z < hi) atomicAdd(&h[db.z - lo], 1);
                if (db.w >= lo && db.w < hi) atomicAdd(&h[db.w - lo], 1);
            }
        }
    } else {
        for (int e = ebeg + (int)threadIdx.x; e < eend; e += 256) {
            int d = __builtin_nontemporal_load(&dst[e]);
            if (d >= lo && d < hi) atomicAdd(&h[d - lo], 1);
        }
    }
    __syncthreads();
    unsigned short* po = partial + (size_t)rep * n + lo;
    for (int i = threadIdx.x; i < cr; i += 256) po[i] = (unsigned short)h[i];
}

// ---------------- scan: per-rep bases + cnt + exclusive rowptr ----------------

__global__ __launch_bounds__(512) void k_scan1(
    const unsigned short* __restrict__ partial, int nrep, int n,
    int* __restrict__ cnt, int* __restrict__ rowptr, int* __restrict__ bsum,
    unsigned short* __restrict__ base)
{
    __shared__ int part[512];
    const int t = threadIdx.x;
    const int i = blockIdx.x * 512 + t;
    int own = 0;
    if (i < n) {
        for (int r = 0; r < nrep; ++r) {
            base[(size_t)r * n + i] = (unsigned short)own;
            own += partial[(size_t)r * n + i];
        }
        cnt[i] = own;
    }
    part[t] = own;
    __syncthreads();
#pragma unroll
    for (int off = 1; off < 512; off <<= 1) {
        int v = (t >= off) ? part[t - off] : 0;
        __syncthreads();
        part[t] += v;
        __syncthreads();
    }
    if (i < n) rowptr[i] = part[t] - own;
    if (t == 511) bsum[blockIdx.x] = part[511];
}

__global__ __launch_bounds__(256) void k_scan2(const int* __restrict__ bsum, int nb,
                                               int* __restrict__ bofs) {
    __shared__ int part[256];
    const int t = threadIdx.x;
    int own = (t < nb) ? bsum[t] : 0;
    part[t] = own;
    __syncthreads();
#pragma unroll
    for (int off = 1; off < 256; off <<= 1) {
        int v = (t >= off) ? part[t - off] : 0;
        __syncthreads();
        part[t] += v;
        __syncthreads();
    }
    if (t < nb) bofs[t] = part[t] - own;
}

__global__ void k_scan3(const int* __restrict__ cnt, int n, int E,
                        const int* __restrict__ bofs, int* __restrict__ rowptr,
                        int* __restrict__ cursor, float* __restrict__ dinv) {
    int i = blockIdx.x * blockDim.x + threadIdx.x;
    if (i >= n) return;
    int rp = rowptr[i] + bofs[i >> 9];
    rowptr[i] = rp;
    cursor[i] = rp;
    dinv[i] = rsqrtf((float)(cnt[i] + 1));
    if (i == 0) rowptr[n] = E;
}

// ---------------- CSR fill: LDS cursors, NO global atomics (4 classes, 8-deep) ----------------

__global__ __launch_bounds__(256) void k_fill_np(
    const int* __restrict__ src, const int* __restrict__ dst, int E, int n, int nrep,
    const int* __restrict__ rowptr, const unsigned short* __restrict__ base,
    int* __restrict__ csr)
{
    __shared__ int cur[HIST_RANGE];
    const int cls = blockIdx.x & 3;
    const int rep = blockIdx.x >> 2;
    const int range = (n + 3) >> 2;
    const int lo = cls * range;
    const int hi = min(n, lo + range);
    const int cr = hi - lo;
    if (cr <= 0) return;
    const unsigned short* bp = base + (size_t)rep * n + lo;
    for (int i = threadIdx.x; i < cr; i += 256) cur[i] = rowptr[lo + i] + (int)bp[i];
    __syncthreads();
    const int chunk = (((E + nrep - 1) / nrep) + 2047) & ~2047;
    const int ebeg = rep * chunk;
    const int eend = min(E, ebeg + chunk);
    if ((E & 3) == 0) {
        for (int e = ebeg + (int)threadIdx.x * 4; e < eend; e += 2048) {
            i32x4 da = __builtin_nontemporal_load((const i32x4*)(dst + e));
            int e2 = e + 1024;
            bool has2 = e2 < eend;
            i32x4 db;
            if (has2) db = __builtin_nontemporal_load((const i32x4*)(dst + e2));
            {
                bool m0 = da.x >= lo && da.x < hi;
                bool m1 = da.y >= lo && da.y < hi;
                bool m2 = da.z >= lo && da.z < hi;
                bool m3 = da.w >= lo && da.w < hi;
                if (m0 | m1 | m2 | m3) {
                    i32x4 s4 = __builtin_nontemporal_load((const i32x4*)(src + e));
                    if (m0) { int p = atomicAdd(&cur[da.x - lo], 1); csr[p] = s4.x; }
                    if (m1) { int p = atomicAdd(&cur[da.y - lo], 1); csr[p] = s4.y; }
                    if (m2) { int p = atomicAdd(&cur[da.z - lo], 1); csr[p] = s4.z; }
                    if (m3) { int p = atomicAdd(&cur[da.w - lo], 1); csr[p] = s4.w; }
                }
            }
            if (has2) {
                bool m0 = db.x >= lo && db.x < hi;
                bool m1 = db.y >= lo && db.y < hi;
                bool m2 = db.z >= lo && db.z < hi;
                bool m3 = db.w >= lo && db.w < hi;
                if (m0 | m1 | m2 | m3) {
                    i32x4 s4 = __builtin_nontemporal_load((const i32x4*)(src + e2));
                    if (m0) { int p = atomicAdd(&cur[db.x - lo], 1); csr[p] = s4.x; }
                    if (m1) { int p = atomicAdd(&cur[db.y - lo], 1); csr[p] = s4.y; }
                    if (m2) { int p = atomicAdd(&cur[db.z - lo], 1); csr[p] = s4.z; }
                    if (m3) { int p = atomicAdd(&cur[db.w - lo], 1); csr[p] = s4.w; }
                }
            }
        }
    } else {
        for (int e = ebeg + (int)threadIdx.x; e < eend; e += 256) {
            int d = __builtin_nontemporal_load(&dst[e]);
            if (d >= lo && d < hi) {
                int s = __builtin_nontemporal_load(&src[e]);
                int p = atomicAdd(&cur[d - lo], 1);
                csr[p] = s;
            }
        }
    }
}

__global__ __launch_bounds__(256) void k_fill_part(
    const int* __restrict__ src, const int* __restrict__ dst, int E, int n,
    int* __restrict__ cursor, int* __restrict__ csr)
{
    const int range = blockIdx.x & 7;
    const int chunk = blockIdx.x >> 3;
    const int nchunks = gridDim.x >> 3;
    const int lo = (int)(((long long)n * range) >> 3);
    const int hi = (int)(((long long)n * (range + 1)) >> 3);
    for (int e = chunk * 256 + (int)threadIdx.x; e < E; e += nchunks * 256) {
        int d = __builtin_nontemporal_load(&dst[e]);
        if (d >= lo && d < hi) {
            int s = __builtin_nontemporal_load(&src[e]);
            int pos = atomicAdd(&cursor[d], 1);
            csr[pos] = s;
        }
    }
}

// ---------------- fused fp32 -> bf16 (RNE) convert for x and gx ----------------

__global__ __launch_bounds__(256) void k_split2(const float* __restrict__ x,
                                                const float* __restrict__ gx,
                                                unsigned short* __restrict__ Ox,
                                                unsigned short* __restrict__ Og, int n8) {
    int i = blockIdx.x * blockDim.x + threadIdx.x;
    const float* in; unsigned short* O; int k;
    if (i < n8) { in = x; O = Ox; k = i; }
    else if (i < 2 * n8) { in = gx; O = Og; k = i - n8; }
    else return;
    f32x4 v0 = ((const f32x4*)in)[k * 2];
    f32x4 v1 = ((const f32x4*)in)[k * 2 + 1];
    bf16x8 o;
#pragma unroll
    for (int j = 0; j < 8; ++j) {
        float f = (j < 4) ? v0[j] : v1[j - 4];
        o[j] = (short)bf16_rne(f);
    }
    *(bf16x8*)(O + (size_t)k * 8) = o;
}

// ---------------- fused weight conversion: all 6 weights in one launch ----------------

struct WCArgs {
    const float* W[6];
    unsigned short* WH[6];
    unsigned short* WL[6];
    int K[6], F[6];
    int tofs[7];
};

__global__ __launch_bounds__(256) void k_wconv_all(WCArgs a) {
    int idx = blockIdx.x * blockDim.x + threadIdx.x;
    if (idx >= a.tofs[6]) return;
    int s = 0;
    while (idx >= a.tofs[s + 1]) ++s;
    int t0 = idx - a.tofs[s];
    const float* W = a.W[s];
    int K = a.K[s], F = a.F[s];
    int lane = t0 & 63;
    int t = t0 >> 6;
    int CT = F / 16;
    int ks = t / CT, ct = t % CT;
    int col = ct * 16 + (lane & 15);
    int kbase = ks * 32 + (lane >> 4) * 8;
    bf16x8 h, l;
#pragma unroll
    for (int j = 0; j < 8; ++j) {
        unsigned short hi, lo;
        split_bf16(W[(size_t)(kbase + j) * F + col], hi, lo);
        h[j] = (short)hi; l[j] = (short)lo;
    }
    *(bf16x8*)(a.WH[s] + (size_t)t0 * 8) = h;
    *(bf16x8*)(a.WL[s] + (size_t)t0 * 8) = l;
}

// ---------------- LDS staging helpers ----------------

__device__ __forceinline__ void stage_load(const unsigned short* Ap, int row0, int n, int tid,
                                           bf16x8& s0, bf16x8& s1) {
    int row = tid >> 3;
    int cb = (tid & 7) << 5;
    int gr = min(row0 + row, n - 1);
    const char* gp = (const char*)Ap + ((size_t)gr << 8) + cb;
    s0 = *(const bf16x8*)gp;
    s1 = *(const bf16x8*)(gp + 16);
}

__device__ __forceinline__ void stage_write(unsigned short* td, int tid, bf16x8 s0, bf16x8 s1) {
    int row = tid >> 3;
    int cb = (tid & 7) << 5;
    int s = (row & 7) << 4;
    char* t = (char*)td + row * 256;
    *(bf16x8*)(t + (cb ^ s)) = s0;
    *(bf16x8*)(t + ((cb + 16) ^ s)) = s1;
}

// ---------------- LDS-staged MFMA GEMM (single-bf16 A, hi/lo W) ----------------
// EPI 0: fp32 out. EPI 1: fp8 e4m3 = dinv*acc. EPI 2: bf16 out (+bias/relu/ bf16 post).
template<int K, int F, int EPI, bool RELU, bool BIAS, bool SUM2, bool POSTADD>
__global__ __launch_bounds__(256, 3) void k_sgemm(
    const unsigned short* __restrict__ A0, const unsigned short* __restrict__ A1,
    const unsigned short* __restrict__ A2,
    const unsigned short* __restrict__ WH, const unsigned short* __restrict__ WL,
    const float* __restrict__ bias, const unsigned short* __restrict__ post,
    const float* __restrict__ dinv, void* __restrict__ o1, int n)
{
    constexpr int CT = F / 16;
    constexpr int CTW = CT / 4;
    constexpr int NCH = K / 128;
    __shared__ unsigned short tile[2][32 * 128];   // 16 KB
    const int tid = threadIdx.x;
    const int lane = tid & 63;
    const int wave = tid >> 6;
    const int row0 = blockIdx.x * 32;
    const int arow = lane & 15;
    const int kgrp = lane >> 4;

    f32x4 acc[2][CTW];
#pragma unroll
    for (int rt = 0; rt < 2; ++rt)
#pragma unroll
        for (int c = 0; c < CTW; ++c) acc[rt][c] = (f32x4)(0.f);

    bf16x8 p0, p1;
    stage_load(A0, row0, n, tid, p0, p1);
    stage_write(tile[0], tid, p0, p1);
    if constexpr (SUM2) {
        stage_load(A1, row0, n, tid, p0, p1);
        stage_write(tile[1], tid, p0, p1);
    }

#pragma unroll
    for (int ch = 0; ch < NCH; ++ch) {
        __syncthreads();
        if (ch + 1 < NCH) {
            const unsigned short* Apn = (ch + 1 == 1) ? A1 : A2;
            stage_load(Apn, row0, n, tid, p0, p1);
        }
        bf16x8 bh[4][CTW], bl[4][CTW];
#pragma unroll
        for (int ks = 0; ks < 4; ++ks)
#pragma unroll
            for (int c = 0; c < CTW; ++c) {
                int ct = wave * CTW + c;
                size_t fo = (((size_t)(ch * 4 + ks) * CT + ct) * 64 + lane) * 8;
                bh[ks][c] = *(const bf16x8*)(WH + fo);
                bl[ks][c] = *(const bf16x8*)(WL + fo);
            }
        int tsrc = SUM2 ? 0 : (ch & 1);
        bf16x8 a[2][4];
#pragma unroll
        for (int rt = 0; rt < 2; ++rt)
#pragma unroll
            for (int ks = 0; ks < 4; ++ks) {
                int row = rt * 16 + arow;
                int cb = (ks * 64 + kgrp * 16) ^ ((row & 7) << 4);
                a[rt][ks] = *(const bf16x8*)((const char*)tile[tsrc] + row * 256 + cb);
            }
        bf16x8 a2f[2][4];
        if constexpr (SUM2) {
#pragma unroll
            for (int rt = 0; rt < 2; ++rt)
#pragma unroll
                for (int ks = 0; ks < 4; ++ks) {
                    int row = rt * 16 + arow;
                    int cb = (ks * 64 + kgrp * 16) ^ ((row & 7) << 4);
                    a2f[rt][ks] = *(const bf16x8*)((const char*)tile[1] + row * 256 + cb);
                }
        }
#pragma unroll
        for (int ks = 0; ks < 4; ++ks)
#pragma unroll
            for (int c = 0; c < CTW; ++c)
#pragma unroll
                for (int rt = 0; rt < 2; ++rt) {
                    acc[rt][c] = __builtin_amdgcn_mfma_f32_16x16x32_bf16(a[rt][ks], bh[ks][c], acc[rt][c], 0, 0, 0);
                    acc[rt][c] = __builtin_amdgcn_mfma_f32_16x16x32_bf16(a[rt][ks], bl[ks][c], acc[rt][c], 0, 0, 0);
                    if constexpr (SUM2) {
                        acc[rt][c] = __builtin_amdgcn_mfma_f32_16x16x32_bf16(a2f[rt][ks], bh[ks][c], acc[rt][c], 0, 0, 0);
                        acc[rt][c] = __builtin_amdgcn_mfma_f32_16x16x32_bf16(a2f[rt][ks], bl[ks][c], acc[rt][c], 0, 0, 0);
                    }
                }
        if (ch + 1 < NCH) stage_write(tile[(ch + 1) & 1], tid, p0, p1);
    }

    // epilogue: D layout col=lane&15, row=(lane>>4)*4+reg  [m89-verified]
    if constexpr (EPI == 1) {
        unsigned char* ob = (unsigned char*)o1;
        float dv[2][4];
#pragma unroll
        for (int rt = 0; rt < 2; ++rt)
#pragma unroll
            for (int r = 0; r < 4; ++r) {
                int row = row0 + rt * 16 + kgrp * 4 + r;
                dv[rt][r] = (row < n) ? dinv[row] : 0.f;
            }
#pragma unroll
        for (int rt = 0; rt < 2; ++rt)
#pragma unroll
            for (int c = 0; c < CTW; ++c) {
                int j = (wave * CTW + c) * 16 + arow;
#pragma unroll
                for (int r = 0; r < 4; ++r) {
                    int row = row0 + rt * 16 + kgrp * 4 + r;
                    if (row < n) ob[(size_t)row * F + j] = fp8_e4m3(acc[rt][c][r] * dv[rt][r]);
                }
            }
    } else if constexpr (EPI == 2) {
        unsigned short* ob = (unsigned short*)o1;
#pragma unroll
        for (int rt = 0; rt < 2; ++rt)
#pragma unroll
            for (int c = 0; c < CTW; ++c) {
                int j = (wave * CTW + c) * 16 + arow;
                float bv = 0.f;
                if constexpr (BIAS) bv = bias[j];
#pragma unroll
                for (int r = 0; r < 4; ++r) {
                    int row = row0 + rt * 16 + kgrp * 4 + r;
                    if (row < n) {
                        float v = acc[rt][c][r];
                        if constexpr (BIAS) v += bv;
                        if constexpr (RELU) v = fmaxf(v, 0.f);
                        if constexpr (POSTADD)
                            v += __uint_as_float((unsigned int)post[(size_t)row * F + j] << 16);
                        ob[(size_t)row * F + j] = bf16_rne(v);
                    }
                }
            }
    } else {
        float* ofp = (float*)o1;
#pragma unroll
        for (int rt = 0; rt < 2; ++rt)
#pragma unroll
            for (int c = 0; c < CTW; ++c) {
                int j = (wave * CTW + c) * 16 + arow;
                float bv = 0.f;
                if constexpr (BIAS) bv = bias[j];
#pragma unroll
                for (int r = 0; r < 4; ++r) {
                    int row = row0 + rt * 16 + kgrp * 4 + r;
                    if (row < n) {
                        float v = acc[rt][c][r];
                        if constexpr (BIAS) v += bv;
                        if constexpr (RELU) v = fmaxf(v, 0.f);
                        ofp[(size_t)row * F + j] = v;
                    }
                }
            }
    }
}

// ---------------- dual GEMM: z0 = ZB@Wdr + bdr (bf16) AND hs1 = dinv*((ZB+XgB)@Wg1) (fp8) ----------------
// Stages ZB and XgB tiles ONCE; two accumulator sets. K=128, F=128.

__global__ __launch_bounds__(256, 2) void k_dgemm(
    const unsigned short* __restrict__ ZB, const unsigned short* __restrict__ XgB,
    const unsigned short* __restrict__ WdH, const unsigned short* __restrict__ WdL,
    const unsigned short* __restrict__ WgH, const unsigned short* __restrict__ WgL,
    const float* __restrict__ bdr, const float* __restrict__ dinv,
    unsigned short* __restrict__ Z0B, unsigned char* __restrict__ HS, int n)
{
    constexpr int F = 128, CT = 8, CTW = 2;
    __shared__ unsigned short tile[2][32 * 128];
    const int tid = threadIdx.x;
    const int lane = tid & 63;
    const int wave = tid >> 6;
    const int row0 = blockIdx.x * 32;
    const int arow = lane & 15;
    const int kgrp = lane >> 4;

    f32x4 accZ[2][CTW], accH[2][CTW];
#pragma unroll
    for (int rt = 0; rt < 2; ++rt)
#pragma unroll
        for (int c = 0; c < CTW; ++c) { accZ[rt][c] = (f32x4)(0.f); accH[rt][c] = (f32x4)(0.f); }

    bf16x8 p0, p1;
    stage_load(ZB, row0, n, tid, p0, p1);
    stage_write(tile[0], tid, p0, p1);
    stage_load(XgB, row0, n, tid, p0, p1);
    stage_write(tile[1], tid, p0, p1);
    __syncthreads();

    bf16x8 a[2][4], g[2][4];
#pragma unroll
    for (int rt = 0; rt < 2; ++rt)
#pragma unroll
        for (int ks = 0; ks < 4; ++ks) {
            int row = rt * 16 + arow;
            int cb = (ks * 64 + kgrp * 16) ^ ((row & 7) << 4);
            a[rt][ks] = *(const bf16x8*)((const char*)tile[0] + row * 256 + cb);
            g[rt][ks] = *(const bf16x8*)((const char*)tile[1] + row * 256 + cb);
        }
#pragma unroll
    for (int ks = 0; ks < 4; ++ks)
#pragma unroll
        for (int c = 0; c < CTW; ++c) {
            int ct = wave * CTW + c;
            size_t fo = (((size_t)ks * CT + ct) * 64 + lane) * 8;
            bf16x8 dh = *(const bf16x8*)(WdH + fo);
            bf16x8 dl = *(const bf16x8*)(WdL + fo);
            bf16x8 gh = *(const bf16x8*)(WgH + fo);
            bf16x8 gl = *(const bf16x8*)(WgL + fo);
#pragma unroll
            for (int rt = 0; rt < 2; ++rt) {
                accZ[rt][c] = __builtin_amdgcn_mfma_f32_16x16x32_bf16(a[rt][ks], dh, accZ[rt][c], 0, 0, 0);
                accZ[rt][c] = __builtin_amdgcn_mfma_f32_16x16x32_bf16(a[rt][ks], dl, accZ[rt][c], 0, 0, 0);
                accH[rt][c] = __builtin_amdgcn_mfma_f32_16x16x32_bf16(a[rt][ks], gh, accH[rt][c], 0, 0, 0);
                accH[rt][c] = __builtin_amdgcn_mfma_f32_16x16x32_bf16(a[rt][ks], gl, accH[rt][c], 0, 0, 0);
                accH[rt][c] = __builtin_amdgcn_mfma_f32_16x16x32_bf16(g[rt][ks], gh, accH[rt][c], 0, 0, 0);
                accH[rt][c] = __builtin_amdgcn_mfma_f32_16x16x32_bf16(g[rt][ks], gl, accH[rt][c], 0, 0, 0);
            }
        }

    float dv[2][4];
#pragma unroll
    for (int rt = 0; rt < 2; ++rt)
#pragma unroll
        for (int r = 0; r < 4; ++r) {
            int row = row0 + rt * 16 + kgrp * 4 + r;
            dv[rt][r] = (row < n) ? dinv[row] : 0.f;
        }
#pragma unroll
    for (int rt = 0; rt < 2; ++rt)
#pragma unroll
        for (int c = 0; c < CTW; ++c) {
            int j = (wave * CTW + c) * 16 + arow;
            float bv = bdr[j];
#pragma unroll
            for (int r = 0; r < 4; ++r) {
                int row = row0 + rt * 16 + kgrp * 4 + r;
                if (row < n) {
                    Z0B[(size_t)row * F + j] = bf16_rne(accZ[rt][c][r] + bv);
                    HS[(size_t)row * F + j] = fp8_e4m3(accH[rt][c][r] * dv[rt][r]);
                }
            }
        }
}

// ---------------- GCN aggregation: fp8 features, 8-deep gather pipeline ----------------

#define ACCW(w) { f32x2 lo_ = __builtin_amdgcn_cvt_pk_f32_fp8((int)(w), false); \
                  f32x2 hi_ = __builtin_amdgcn_cvt_pk_f32_fp8((int)(w), true);  \
                  a0 += lo_.x; a1 += lo_.y; a2 += hi_.x; a3 += hi_.y; }

__global__ __launch_bounds__(256) void k_agg_bf(
    const int* __restrict__ rowptr, const int* __restrict__ csr,
    const float* __restrict__ dinv, const unsigned char* __restrict__ hs,
    const float* __restrict__ bias, unsigned short* __restrict__ outB, int n)
{
    const int node = blockIdx.x * 8 + (threadIdx.x >> 5);
    if (node >= n) return;
    const int c = threadIdx.x & 31;
    const float dd = dinv[node];
    const int beg = rowptr[node];
    const int end = rowptr[node + 1];
    const unsigned int* hw = (const unsigned int*)hs;

    float a0 = 0.f, a1 = 0.f, a2 = 0.f, a3 = 0.f;
    {
        unsigned int w = hw[(size_t)node * 32 + c];
        ACCW(w)
    }

    int j = beg;
    for (; j + 7 < end; j += 8) {
        int s0 = csr[j],     s1 = csr[j + 1], s2 = csr[j + 2], s3 = csr[j + 3];
        int s4 = csr[j + 4], s5 = csr[j + 5], s6 = csr[j + 6], s7 = csr[j + 7];
        unsigned int w0 = hw[(size_t)s0 * 32 + c];
        unsigned int w1 = hw[(size_t)s1 * 32 + c];
        unsigned int w2 = hw[(size_t)s2 * 32 + c];
        unsigned int w3 = hw[(size_t)s3 * 32 + c];
        unsigned int w4 = hw[(size_t)s4 * 32 + c];
        unsigned int w5 = hw[(size_t)s5 * 32 + c];
        unsigned int w6 = hw[(size_t)s6 * 32 + c];
        unsigned int w7 = hw[(size_t)s7 * 32 + c];
        ACCW(w0) ACCW(w1) ACCW(w2) ACCW(w3)
        ACCW(w4) ACCW(w5) ACCW(w6) ACCW(w7)
    }
    for (; j + 3 < end; j += 4) {
        int s0 = csr[j], s1 = csr[j + 1], s2 = csr[j + 2], s3 = csr[j + 3];
        unsigned int w0 = hw[(size_t)s0 * 32 + c];
        unsigned int w1 = hw[(size_t)s1 * 32 + c];
        unsigned int w2 = hw[(size_t)s2 * 32 + c];
        unsigned int w3 = hw[(size_t)s3 * 32 + c];
        ACCW(w0) ACCW(w1) ACCW(w2) ACCW(w3)
    }
    for (; j < end; ++j) {
        unsigned int w = hw[(size_t)csr[j] * 32 + c];
        ACCW(w)
    }

    float4 bv = ((const float4*)bias)[c];
    ushort4 h4;
    h4.x = bf16_rne(fmaxf(fmaf(dd, a0, bv.x), 0.f));
    h4.y = bf16_rne(fmaxf(fmaf(dd, a1, bv.y), 0.f));
    h4.z = bf16_rne(fmaxf(fmaf(dd, a2, bv.z), 0.f));
    h4.w = bf16_rne(fmaxf(fmaf(dd, a3, bv.w), 0.f));
    *(ushort4*)(outB + (size_t)node * 128 + c * 4) = h4;
}

// ---------------- final small GEMM [n,64]@[64,10] ----------------

__global__ __launch_bounds__(256) void k_final(const float* __restrict__ z7, const float* __restrict__ Wo,
                        const float* __restrict__ bo, float* __restrict__ out, int n) {
    __shared__ float Wos[64][10];
    __shared__ float bos[10];
    if (threadIdx.x < 64) {
#pragma unroll
        for (int j = 0; j < 10; ++j) Wos[threadIdx.x][j] = Wo[threadIdx.x * 10 + j];
        if (threadIdx.x < 10) bos[threadIdx.x] = bo[threadIdx.x];
    }
    __syncthreads();
    int idx = blockIdx.x * blockDim.x + threadIdx.x;
    if (idx >= n * 10) return;
    int row = idx / 10, j = idx % 10;
    const float* zr = z7 + (size_t)row * 64;
    float acc = bos[j];
#pragma unroll
    for (int k = 0; k < 64; ++k) acc = fmaf(zr[k], Wos[k][j], acc);
    out[idx] = acc;
}

// ---------------- launch ----------------

extern "C" void kernel_launch(void* const* d_in, const int* in_sizes, int n_in,
                              void* d_out, int out_size, void* d_ws, size_t ws_size,
                              hipStream_t stream) {
    const float* x   = (const float*)d_in[0];
    const float* gx  = (const float*)d_in[1];
    const void*  ei  = d_in[2];
    const float* W1  = (const float*)d_in[3];  const float* b1  = (const float*)d_in[4];
    const float* Wdr = (const float*)d_in[5];  const float* bdr = (const float*)d_in[6];
    const float* Wg1 = (const float*)d_in[7];  const float* bg1 = (const float*)d_in[8];
    const float* Wg2 = (const float*)d_in[9];  const float* bg2 = (const float*)d_in[10];
    const float* W2  = (const float*)d_in[11]; const float* b2  = (const float*)d_in[12];
    const float* W3  = (const float*)d_in[13]; const float* b3  = (const float*)d_in[14];
    const float* Wo  = (const float*)d_in[15]; const float* bo  = (const float*)d_in[16];
    float* out = (float*)d_out;
    const int n = in_sizes[0] / 128;
    const int E = in_sizes[2] / 2;
    const int twoE = 2 * E;
    const int nb = (n + 511) / 512;
    const int NREP = 128;

    char* ws = (char*)d_ws;
    size_t off = 0;
    auto alloc = [&](size_t bytes) -> void* {
        void* p = ws + off;
        off = (off + bytes + 255) & ~(size_t)255;
        return p;
    };
    int*   flag   = (int*)  alloc(256);
    int*   cnt    = (int*)  alloc((size_t)n * 4);
    int*   rowptr = (int*)  alloc(((size_t)n + 1) * 4);
    int*   cursor = (int*)  alloc((size_t)n * 4);
    float* dinv   = (float*)alloc((size_t)n * 4);
    int*   bsum   = (int*)  alloc(1024);
    int*   bofs   = (int*)  alloc(1024);
    int*   es     = (int*)  alloc((size_t)twoE * 4);
    int*   ed     = es + E;
    int*   csr    = (int*)  alloc((size_t)E * 4);
    unsigned short* W1H  = (unsigned short*)alloc(256 * 128 * 2);
    unsigned short* W1L  = (unsigned short*)alloc(256 * 128 * 2);
    unsigned short* WdrH = (unsigned short*)alloc(128 * 128 * 2);
    unsigned short* WdrL = (unsigned short*)alloc(128 * 128 * 2);
    unsigned short* Wg1H = (unsigned short*)alloc(128 * 128 * 2);
    unsigned short* Wg1L = (unsigned short*)alloc(128 * 128 * 2);
    unsigned short* Wg2H = (unsigned short*)alloc(128 * 128 * 2);
    unsigned short* Wg2L = (unsigned short*)alloc(128 * 128 * 2);
    unsigned short* W2H  = (unsigned short*)alloc(384 * 128 * 2);
    unsigned short* W2L  = (unsigned short*)alloc(384 * 128 * 2);
    unsigned short* W3H  = (unsigned short*)alloc(128 * 64 * 2);
    unsigned short* W3L  = (unsigned short*)alloc(128 * 64 * 2);
    const size_t nf = (size_t)n * 128;
    unsigned short* XaB = (unsigned short*)alloc(nf * 2);   // bf16(x)
    unsigned short* XgB = (unsigned short*)alloc(nf * 2);   // bf16(gx)
    // ARENA: prep-phase partial/base (ushort) aliases post-prep activations.
    size_t prep_bytes = 2 * ((size_t)NREP * n * 2 + 256);
    size_t act_bytes  = (nf * 2 + 256) * 3 + (nf + 256) + ((size_t)n * 64 * 4 + 256);
    char* arena = (char*)alloc(prep_bytes > act_bytes ? prep_bytes : act_bytes);
    unsigned short* partial = (unsigned short*)arena;
    unsigned short* base    = (unsigned short*)(arena + (((size_t)NREP * n * 2 + 255) & ~(size_t)255));
    char* ap = arena;
    auto carve = [&](size_t bytes) -> void* {
        void* p = ap;
        ap += (bytes + 255) & ~(size_t)255;
        return p;
    };
    unsigned short* ZB  = (unsigned short*)carve(nf * 2);   // bf16(z)
    unsigned short* Z1B = (unsigned short*)carve(nf * 2);   // bf16(z1)
    unsigned short* Z0B = (unsigned short*)carve(nf * 2);   // bf16(z0)
    unsigned char*  HS  = (unsigned char*) carve(nf);       // dinv-scaled fp8 h
    float* B1 = (float*)carve((size_t)n * 64 * 4);          // z7 (fp32)
    unsigned short* TB  = XaB;  // t: written by GEMM5 (XaB dead after GEMM1)
    unsigned short* Z2B = XgB;  // z2: written by agg2 (XgB dead after dgemm)
    unsigned char*  HS2 = HS;   // HS dead after agg1
    (void)ws_size; (void)n_in; (void)out_size;

    // edge prep + CSR build
    k_detect<<<1, 64, 0, stream>>>((const unsigned int*)ei, flag);
    k_convert<<<(twoE / 2 + 255) / 256, 256, 0, stream>>>(ei, twoE, flag, es);
    if (n <= 4 * HIST_RANGE) {
        k_hist_part<<<4 * NREP, 256, 0, stream>>>(ed, E, n, NREP, partial);
        k_scan1<<<nb, 512, 0, stream>>>(partial, NREP, n, cnt, rowptr, bsum, base);
        k_scan2<<<1, 256, 0, stream>>>(bsum, nb, bofs);
        k_scan3<<<(n + 255) / 256, 256, 0, stream>>>(cnt, n, E, bofs, rowptr, cursor, dinv);
        k_fill_np<<<4 * NREP, 256, 0, stream>>>(es, ed, E, n, NREP, rowptr, base, csr);
    } else {
        hipMemsetAsync(cnt, 0, (size_t)n * 4, stream);
        k_hist_atomic<<<(E + 255) / 256, 256, 0, stream>>>(ed, E, cnt);
        k_scan1<<<nb, 512, 0, stream>>>((const unsigned short*)nullptr, 0, n, cnt, rowptr, bsum, base);
        k_scan2<<<1, 256, 0, stream>>>(bsum, nb, bofs);
        k_scan3<<<(n + 255) / 256, 256, 0, stream>>>(cnt, n, E, bofs, rowptr, cursor, dinv);
        k_fill_part<<<2048, 256, 0, stream>>>(es, ed, E, n, cursor, csr);
    }

    // fused weight + activation converts
    {
        WCArgs a;
        const float* Ws[6] = { W1, Wdr, Wg1, Wg2, W2, W3 };
        unsigned short* WHs[6] = { W1H, WdrH, Wg1H, Wg2H, W2H, W3H };
        unsigned short* WLs[6] = { W1L, WdrL, Wg1L, Wg2L, W2L, W3L };
        int Ks[6] = { 256, 128, 128, 128, 384, 128 };
        int Fs[6] = { 128, 128, 128, 128, 128, 64 };
        int acc = 0;
        for (int s = 0; s < 6; ++s) {
            a.W[s] = Ws[s]; a.WH[s] = WHs[s]; a.WL[s] = WLs[s];
            a.K[s] = Ks[s]; a.F[s] = Fs[s];
            a.tofs[s] = acc;
            acc += Ks[s] * Fs[s] / 8;
        }
        a.tofs[6] = acc;
        k_wconv_all<<<(acc + 255) / 256, 256, 0, stream>>>(a);
    }
    const int n8 = n * 16;
    k_split2<<<(2 * n8 + 255) / 256, 256, 0, stream>>>(x, gx, XaB, XgB, n8);

    const int gm = (n + 31) / 32;
    const int ga = (n + 7) / 8;
    // z = relu([x|gx] @ W1 + b1)  -> ZB
    k_sgemm<256, 128, 2, true,  true,  false, false><<<gm, 256, 0, stream>>>(
        XaB, XgB, nullptr, W1H, W1L, b1, nullptr, nullptr, ZB, n);
    // DUAL: z0 = z@Wdr + bdr (bf16) AND hs1 = fp8(dinv*((z+gx)@Wg1))
    k_dgemm<<<gm, 256, 0, stream>>>(ZB, XgB, WdrH, WdrL, Wg1H, Wg1L, bdr, dinv, Z0B, HS, n);
    // z1 = relu(dinv*(hs1[d] + sum hs1[s]) + bg1) -> Z1B
    k_agg_bf<<<ga, 256, 0, stream>>>(rowptr, csr, dinv, HS, bg1, Z1B, n);
    // hs2 = fp8(dinv * (z1 @ Wg2)) -> HS2
    k_sgemm<128, 128, 1, false, false, false, false><<<gm, 256, 0, stream>>>(
        Z1B, nullptr, nullptr, Wg2H, Wg2L, nullptr, nullptr, dinv, HS2, n);
    // z2 = relu(dinv*(hs2[d] + sum hs2[s]) + bg2) -> Z2B
    k_agg_bf<<<ga, 256, 0, stream>>>(rowptr, csr, dinv, HS2, bg2, Z2B, n);
    // t = relu([z|z1|z2] @ W2 + b2) + z0 -> TB
    k_sgemm<384, 128, 2, true,  true,  false, true ><<<gm, 256, 0, stream>>>(
        ZB, Z1B, Z2B, W2H, W2L, b2, Z0B, nullptr, TB, n);
    // z7 = relu(t @ W3 + b3) -> B1 (fp32)
    k_sgemm<128, 64,  0, true,  true,  false, false><<<gm, 256, 0, stream>>>(
        TB, nullptr, nullptr, W3H, W3L, b3, nullptr, nullptr, B1, n);
    // out = z7 @ Wo + bo
    k_final<<<(n * 10 + 255) / 256, 256, 0, stream>>>(B1, Wo, bo, out, n);
}